// Round 8
// baseline (413.141 us; speedup 1.0000x reference)
//
#include <hip/hip_runtime.h>

namespace {

constexpr int B = 64, N = 64, D = 64, E = 2 * D + 1;  // E = 129
constexpr int NBLK = 512;            // 2 blocks/CU, guaranteed co-resident
constexpr size_t MAXSLOT = 1024;
constexpr int LMAX = 8;

__device__ __forceinline__ float4 f4ld(const float* p) { return *(const float4*)p; }
__device__ __forceinline__ void f4acc(float4& a, const float4 b) {
  a.x += b.x; a.y += b.y; a.z += b.z; a.w += b.w;
}

// Device-scope grid barrier. Arrive = ONE atomic RMW per block; poll = relaxed
// device-scope atomic LOAD (read-shared, no RMW serialization storm).
__device__ __forceinline__ void gridbar(unsigned* cnt) {
  __syncthreads();
  if (threadIdx.x == 0) {
    __threadfence();  // release: prior writes visible device-wide
    __hip_atomic_fetch_add(cnt, 1u, __ATOMIC_RELAXED, __HIP_MEMORY_SCOPE_AGENT);
    while (__hip_atomic_load(cnt, __ATOMIC_RELAXED, __HIP_MEMORY_SCOPE_AGENT) <
           (unsigned)NBLK)
      __builtin_amdgcn_s_sleep(32);
    __threadfence();  // acquire: invalidate stale caches
  }
  __syncthreads();
}

__global__ __launch_bounds__(256, 2) void k_fused(
    const float* __restrict__ x,   // [B][N][D]
    const float* __restrict__ ew,  // [N][N]
    const float* __restrict__ Wm,  // [L][N][N][E][D]
    const float* __restrict__ bm,  // [L][N][N][D]
    const float* __restrict__ Wu,  // [L][2D][D]
    const float* __restrict__ bu,  // [L][D]
    const float* __restrict__ Wo,  // [D][D]
    const float* __restrict__ bo,  // [D]
    float* __restrict__ out,       // [B][D]
    char* __restrict__ ws, int L)
{
  // ---- workspace carve (bar at offset 0; memset-zeroed each launch) ----
  unsigned* bar = (unsigned*)ws;
  char* p = ws + 256;
  float* s       = (float*)p; p += (size_t)B * N * D * 4;
  float* selfmsg = (float*)p; p += (size_t)N * B * D * 4;
  float* msg     = (float*)p; p += MAXSLOT * B * D * 4;
  float* sw1     = (float*)p; p += (size_t)LMAX * N * D * D * 4;
  float* baseB   = (float*)p; p += (size_t)LMAX * N * D * 4;
  uint4* nbr4    = (uint4*)p; p += N * 16;
  float* degf    = (float*)p; p += N * 4;
  float* cwg     = (float*)p; p += N * 4;
  int* cntg      = (int*)p;   p += N * 4;
  int* rowbase   = (int*)p;   p += N * 4;
  int* edgeIJ    = (int*)p;   p += MAXSLOT * 4;
  int* nedg      = (int*)p;   p += 16;
  unsigned char* nfull = (unsigned char*)p;  // [N][N]

  __shared__ __align__(16) char pool[51200];

  const int g = blockIdx.x;
  const int t = threadIdx.x;

  // ================= P0: prep (block 0) + W1-sum/base (blocks 1..L*N) ======
  if (g == 0) {
    if (t < N) {
      int rc = 0;
      for (int j = 0; j < N; ++j) rc += (ew[t * N + j] > 0.f) ? 1 : 0;
      int pre = rc;
#pragma unroll
      for (int off = 1; off < 64; off <<= 1) {
        int v = __shfl_up(pre, off, 64);
        if (t >= off) pre += v;
      }
      const int base = pre - rc;  // exclusive prefix
      rowbase[t] = base;
      unsigned long long lo = 0ull, hi = 0ull;
      int c = 0;
      float rowsum = 0.f;
      for (int j = 0; j < N; ++j) {
        const float v = ew[t * N + j];
        rowsum += v;
        if (v > 0.f) {
          edgeIJ[base + c] = t * N + j;
          if (c < 8)       lo |= (unsigned long long)j << (c * 8);
          else if (c < 16) hi |= (unsigned long long)j << ((c - 8) * 8);
          nfull[t * N + c] = (unsigned char)j;
          ++c;
        }
      }
      uint4 w4;
      w4.x = (unsigned)lo; w4.y = (unsigned)(lo >> 32);
      w4.z = (unsigned)hi; w4.w = (unsigned)(hi >> 32);
      nbr4[t] = w4; cntg[t] = c; degf[t] = (float)c;
      float tot = rowsum;
#pragma unroll
      for (int off = 32; off >= 1; off >>= 1) tot += __shfl_xor(tot, off, 64);
      cwg[t] = rowsum / (tot + 1e-8f);
      if (t == 63) *nedg = pre;  // total edge count
    }
  } else if (g <= L * N) {
    // SW1[l][i] = sum_{j in N(i)} W1_{l,i,j};  base[l][i] = sum_j (w*W3 + b)
    const int unit = g - 1, l = unit >> 6, i = unit & 63;
    const float* Wl = Wm + (size_t)l * N * N * E * D;
    float4 a0 = {0,0,0,0}, a1 = {0,0,0,0}, a2 = {0,0,0,0}, a3 = {0,0,0,0};
    float4 bacc = {0,0,0,0};
    for (int j = 0; j < N; ++j) {
      const float v = ew[i * N + j];
      if (v > 0.f) {
        const float* Wp = Wl + (size_t)(i * N + j) * (E * D);
        f4acc(a0, f4ld(Wp + (0 * 256 + t) * 4));
        f4acc(a1, f4ld(Wp + (1 * 256 + t) * 4));
        f4acc(a2, f4ld(Wp + (2 * 256 + t) * 4));
        f4acc(a3, f4ld(Wp + (3 * 256 + t) * 4));
        if (t < 16) {
          const float4 w3 = f4ld(Wp + 2 * D * D + t * 4);
          const float4 bv = f4ld(bm + (((size_t)l * N + i) * N + j) * D + t * 4);
          bacc.x += v * w3.x + bv.x;
          bacc.y += v * w3.y + bv.y;
          bacc.z += v * w3.z + bv.z;
          bacc.w += v * w3.w + bv.w;
        }
      }
    }
    float* dst = sw1 + (size_t)unit * D * D;
    *(float4*)(dst + (0 * 256 + t) * 4) = a0;
    *(float4*)(dst + (1 * 256 + t) * 4) = a1;
    *(float4*)(dst + (2 * 256 + t) * 4) = a2;
    *(float4*)(dst + (3 * 256 + t) * 4) = a3;
    if (t < 16) *(float4*)(baseB + (size_t)unit * D + t * 4) = bacc;
  }
  gridbar(bar + 0);

  for (int l = 0; l < L; ++l) {
    const float* sin_p = (l == 0) ? x : s;
    const bool LAST = (l == L - 1);
    const float* Wl = Wm + (size_t)l * N * N * E * D;

    // ================= P1: per-edge K=64 GEMMs + per-node self GEMMs ======
    {
      float (*aT)[64] = (float(*)[64])pool;        // 16KB: aT[k][b] = S[b][jj][k]
      float* wLds = (float*)(pool + 16384);        // 16KB

      const int ne = *nedg;
      for (int u = g; u < ne + N; u += NBLK) {
        int jj;
        const float* wsrc;
        const float* basep;
        float* dst;
        if (u < ne) {
          const int ij = edgeIJ[u];
          jj = ij & 63;
          wsrc = Wl + (size_t)ij * (E * D) + D * D;      // W2 block
          dst = msg + (size_t)u * B * D;
          basep = nullptr;
        } else {
          const int i = u - ne;
          jj = i;
          wsrc = sw1 + ((size_t)l * N + i) * D * D;
          dst = selfmsg + (size_t)i * B * D;
          basep = baseB + ((size_t)l * N + i) * D;
        }
        // stage A^T
        {
          const int bb = t >> 2, q = t & 3;
          const float* ps = sin_p + ((size_t)(bb * N + jj)) * D + q * 16;
          const float4 v0 = f4ld(ps), v1 = f4ld(ps + 4),
                       v2 = f4ld(ps + 8), v3 = f4ld(ps + 12);
          const int k0 = q * 16;
          aT[k0 + 0][bb] = v0.x; aT[k0 + 1][bb] = v0.y;
          aT[k0 + 2][bb] = v0.z; aT[k0 + 3][bb] = v0.w;
          aT[k0 + 4][bb] = v1.x; aT[k0 + 5][bb] = v1.y;
          aT[k0 + 6][bb] = v1.z; aT[k0 + 7][bb] = v1.w;
          aT[k0 + 8][bb] = v2.x; aT[k0 + 9][bb] = v2.y;
          aT[k0 +10][bb] = v2.z; aT[k0 +11][bb] = v2.w;
          aT[k0 +12][bb] = v3.x; aT[k0 +13][bb] = v3.y;
          aT[k0 +14][bb] = v3.z; aT[k0 +15][bb] = v3.w;
        }
        // stage W (16KB, coalesced)
#pragma unroll
        for (int r = 0; r < 4; ++r)
          *(float4*)(wLds + (r * 256 + t) * 4) = f4ld(wsrc + (r * 256 + t) * 4);
        __syncthreads();

        const int td = t & 15, tb = t >> 4;
        float acc[4][4];
        if (basep) {
          const float4 bv = f4ld(basep + td * 4);
#pragma unroll
          for (int r = 0; r < 4; ++r) {
            acc[r][0] = bv.x; acc[r][1] = bv.y;
            acc[r][2] = bv.z; acc[r][3] = bv.w;
          }
        } else {
#pragma unroll
          for (int r = 0; r < 4; ++r)
#pragma unroll
            for (int c2 = 0; c2 < 4; ++c2) acc[r][c2] = 0.f;
        }
#pragma unroll 4
        for (int k = 0; k < D; ++k) {
          const float4 a = *(const float4*)&aT[k][tb * 4];
          const float4 wv = f4ld(wLds + k * D + td * 4);
          const float ar[4] = {a.x, a.y, a.z, a.w};
          const float wc[4] = {wv.x, wv.y, wv.z, wv.w};
#pragma unroll
          for (int r = 0; r < 4; ++r)
#pragma unroll
            for (int c2 = 0; c2 < 4; ++c2) acc[r][c2] += ar[r] * wc[c2];
        }
        float* mp = dst + ((size_t)(tb * 4)) * D + td * 4;
#pragma unroll
        for (int r = 0; r < 4; ++r)
          *(float4*)(mp + (size_t)r * D) =
              make_float4(acc[r][0], acc[r][1], acc[r][2], acc[r][3]);
        __syncthreads();  // LDS reuse by next unit
      }
    }
    gridbar(bar + 1 + 2 * l);

    // ================= P2: update MLP + residual + scan (+ readout) =======
    if (g < B) {
      const int b = g;
      const float* Wul = Wu + (size_t)l * 2 * D * D;
      const float* bul = bu + (size_t)l * D;

      float (*catT)[64] = (float(*)[64])pool;               // 32KB
      float (*sb)[65]   = (float(*)[65])(pool + 32768);     // 16640B
      uint4* nbrL = (uint4*)(pool + 49408);                 // 1KB
      float* degL = (float*)(pool + 50432);
      float* cwL  = (float*)(pool + 50688);
      int*   cntL = (int*)(pool + 50944);

      {
        const int ii = t >> 2, q = t & 3;
        const int cI = cntg[ii];
        const int rb = rowbase[ii];
        float4 a4[4];
#pragma unroll
        for (int kc = 0; kc < 4; ++kc)
          a4[kc] = f4ld(selfmsg + ((size_t)(ii * B + b)) * D + kc * 16 + q * 4);
        for (int e = 0; e < cI; ++e) {
          const float* pm = msg + ((size_t)(rb + e) * B + b) * D;
#pragma unroll
          for (int kc = 0; kc < 4; ++kc)
            f4acc(a4[kc], f4ld(pm + kc * 16 + q * 4));
        }
        const float* ps = sin_p + ((size_t)(b * N + ii)) * D;
#pragma unroll
        for (int kc = 0; kc < 4; ++kc) {
          const int k0 = kc * 16 + q * 4;
          const float4 v = f4ld(ps + k0);
          catT[k0 + 0][ii] = v.x; catT[k0 + 1][ii] = v.y;
          catT[k0 + 2][ii] = v.z; catT[k0 + 3][ii] = v.w;
          catT[D + k0 + 0][ii] = a4[kc].x; catT[D + k0 + 1][ii] = a4[kc].y;
          catT[D + k0 + 2][ii] = a4[kc].z; catT[D + k0 + 3][ii] = a4[kc].w;
        }
      }
      if (t < N) {
        nbrL[t] = nbr4[t];
        degL[t] = degf[t];
        cntL[t] = cntg[t];
        if (LAST) cwL[t] = cwg[t];
      }
      __syncthreads();

      // upd GEMM: lane = i, wave-uniform d-chunk
      const int i = t & 63;
      const int d0 = __builtin_amdgcn_readfirstlane(t >> 6) * 16;
      float acc[16];
#pragma unroll
      for (int u = 0; u < 16; ++u) acc[u] = bul[d0 + u];
#pragma unroll 4
      for (int k = 0; k < 2 * D; ++k) {
        const float a = catT[k][i];
        const float* __restrict__ wr = Wul + (size_t)k * D + d0;
#pragma unroll
        for (int u = 0; u < 16; ++u) acc[u] += a * wr[u];
      }
#pragma unroll
      for (int u = 0; u < 16; ++u)
        sb[i][d0 + u] = 0.9f * acc[u] + 0.1f * catT[d0 + u][i];
      __syncthreads();

      // sequential node scan; lane d owns column d (wave 0)
      if (t < N) {
        const int d = t;
        uint4 w = nbrL[0];
        int c = cntL[0];
        float dg = degL[0];
        for (int ii = 0; ii < N; ++ii) {
          uint4 wn = w; int cn = c; float dgn = dg;
          if (ii < N - 1) { wn = nbrL[ii + 1]; cn = cntL[ii + 1]; dgn = degL[ii + 1]; }
          const unsigned wd[4] = {w.x, w.y, w.z, w.w};
          float nb = 0.0f;
#pragma unroll
          for (int q = 0; q < 8; ++q) {
            const int idx = (int)((wd[q >> 2] >> ((q & 3) * 8)) & 63u);
            const float v = sb[idx][d];
            nb += (q < c) ? v : 0.0f;
          }
          if (c > 8) {
#pragma unroll
            for (int q = 8; q < 16; ++q) {
              const int idx = (int)((wd[q >> 2] >> ((q & 3) * 8)) & 63u);
              const float v = sb[idx][d];
              nb += (q < c) ? v : 0.0f;
            }
            for (int q = 16; q < c; ++q) nb += sb[nfull[ii * N + q]][d];
          }
          const float avg = nb / fmaxf(dg, 1.0f);
          const float cur = sb[ii][d];
          sb[ii][d] = (dg > 0.0f) ? (0.95f * cur + 0.05f * avg) : cur;
          w = wn; c = cn; dg = dgn;
        }
        if (LAST) {
          float gg = 0.0f;
          for (int i2 = 0; i2 < N; ++i2) gg += cwL[i2] * sb[i2][d];
          float o = bo[d];
          for (int k2 = 0; k2 < D; ++k2) o += __shfl(gg, k2, 64) * Wo[k2 * D + d];
          out[(size_t)b * D + d] = o;
        }
      }

      if (!LAST) {
        __syncthreads();
        const int ii = t >> 2, q = t & 3;
        float* ps = s + ((size_t)(b * N + ii)) * D;
#pragma unroll
        for (int kc = 0; kc < 4; ++kc) {
          const int k0 = kc * 16 + q * 4;
          float4 v;
          v.x = sb[ii][k0 + 0]; v.y = sb[ii][k0 + 1];
          v.z = sb[ii][k0 + 2]; v.w = sb[ii][k0 + 3];
          *(float4*)(ps + k0) = v;
        }
      }
    }
    if (l < L - 1) gridbar(bar + 2 + 2 * l);
  }
}

}  // namespace

extern "C" void kernel_launch(void* const* d_in, const int* in_sizes, int n_in,
                              void* d_out, int out_size, void* d_ws, size_t ws_size,
                              hipStream_t stream)
{
  const float* x  = (const float*)d_in[0];
  const float* ew = (const float*)d_in[1];
  const float* Wm = (const float*)d_in[2];
  const float* bm = (const float*)d_in[3];
  const float* Wu = (const float*)d_in[4];
  const float* bu = (const float*)d_in[5];
  const float* Wo = (const float*)d_in[6];
  const float* bo = (const float*)d_in[7];
  float* out = (float*)d_out;

  int L = in_sizes[2] / (N * N * E * D);  // = 3
  if (L > LMAX) L = LMAX;

  hipMemsetAsync(d_ws, 0, 256, stream);  // zero grid-barrier counters
  k_fused<<<NBLK, 256, 0, stream>>>(x, ew, Wm, bm, Wu, bu, Wo, bo, out,
                                    (char*)d_ws, L);
}

// Round 9
// 262.909 us; speedup vs baseline: 1.5714x; 1.5714x over previous
//
#include <hip/hip_runtime.h>

namespace {

constexpr int B = 64, N = 64, D = 64, E = 2 * D + 1;  // E = 129
constexpr int NBLK = 256;            // exactly 1 block per CU
constexpr size_t MAXSLOT = 1024;
constexpr int LMAX = 8;

__device__ __forceinline__ float4 f4ld(const float* p) { return *(const float4*)p; }
__device__ __forceinline__ void f4acc(float4& a, const float4 b) {
  a.x += b.x; a.y += b.y; a.z += b.z; a.w += b.w;
}

// Device-scope grid barrier. Arrive = one RMW per block; poll = relaxed
// device-scope atomic load; fences only around the arrive/release point.
__device__ __forceinline__ void gridbar(unsigned* cnt) {
  __syncthreads();
  if (threadIdx.x == 0) {
    __threadfence();  // release
    __hip_atomic_fetch_add(cnt, 1u, __ATOMIC_RELAXED, __HIP_MEMORY_SCOPE_AGENT);
    while (__hip_atomic_load(cnt, __ATOMIC_RELAXED, __HIP_MEMORY_SCOPE_AGENT) <
           (unsigned)NBLK)
      __builtin_amdgcn_s_sleep(8);
    __threadfence();  // acquire
  }
  __syncthreads();
}

__global__ __launch_bounds__(256) void k_fused(
    const float* __restrict__ x,   // [B][N][D]
    const float* __restrict__ ew,  // [N][N]
    const float* __restrict__ Wm,  // [L][N][N][E][D]
    const float* __restrict__ bm,  // [L][N][N][D]
    const float* __restrict__ Wu,  // [L][2D][D]
    const float* __restrict__ bu,  // [L][D]
    const float* __restrict__ Wo,  // [D][D]
    const float* __restrict__ bo,  // [D]
    float* __restrict__ out,       // [B][D]
    char* __restrict__ ws, int L)
{
  // ---- workspace carve (bar at offset 0; memset-zeroed each launch) ----
  unsigned* bar = (unsigned*)ws;
  char* p = ws + 256;
  float* s       = (float*)p; p += (size_t)B * N * D * 4;
  float* selfmsg = (float*)p; p += (size_t)N * B * D * 4;
  float* msg     = (float*)p; p += MAXSLOT * B * D * 4;
  float* sw1     = (float*)p; p += (size_t)LMAX * N * D * D * 4;
  float* baseB   = (float*)p; p += (size_t)LMAX * N * D * 4;
  uint4* nbr4    = (uint4*)p; p += N * 16;
  float* degf    = (float*)p; p += N * 4;
  float* cwg     = (float*)p; p += N * 4;
  int* cntg      = (int*)p;   p += N * 4;
  int* rowbase   = (int*)p;   p += N * 4;
  int* edgeIJ    = (int*)p;   p += MAXSLOT * 4;
  int* nedg      = (int*)p;   p += 16;
  unsigned char* nfull = (unsigned char*)p;  // [N][N]

  // 64 KB static LDS. P1: aT(16K)+wLds(16K). P2: catT(32K)+wuL(32K);
  // sb+tables OVERLAY wuL after the GEMM (acc is in registers by then).
  __shared__ __align__(16) char pool[65536];

  const int g = blockIdx.x;
  const int t = threadIdx.x;

  // ================= P0: prep (block 0) + W1-sum/base (blocks 1..L*N) ======
  if (g == 0) {
    if (t < N) {
      int rc = 0;
      for (int j = 0; j < N; ++j) rc += (ew[t * N + j] > 0.f) ? 1 : 0;
      int pre = rc;
#pragma unroll
      for (int off = 1; off < 64; off <<= 1) {
        int v = __shfl_up(pre, off, 64);
        if (t >= off) pre += v;
      }
      const int base = pre - rc;  // exclusive prefix
      rowbase[t] = base;
      unsigned long long lo = 0ull, hi = 0ull;
      int c = 0;
      float rowsum = 0.f;
      for (int j = 0; j < N; ++j) {
        const float v = ew[t * N + j];
        rowsum += v;
        if (v > 0.f) {
          edgeIJ[base + c] = t * N + j;
          if (c < 8)       lo |= (unsigned long long)j << (c * 8);
          else if (c < 16) hi |= (unsigned long long)j << ((c - 8) * 8);
          nfull[t * N + c] = (unsigned char)j;
          ++c;
        }
      }
      uint4 w4;
      w4.x = (unsigned)lo; w4.y = (unsigned)(lo >> 32);
      w4.z = (unsigned)hi; w4.w = (unsigned)(hi >> 32);
      nbr4[t] = w4; cntg[t] = c; degf[t] = (float)c;
      float tot = rowsum;
#pragma unroll
      for (int off = 32; off >= 1; off >>= 1) tot += __shfl_xor(tot, off, 64);
      cwg[t] = rowsum / (tot + 1e-8f);
      if (t == 63) *nedg = pre;  // total edge count
    }
  } else if (g <= L * N) {
    // SW1[l][i] = sum_{j in N(i)} W1_{l,i,j};  base[l][i] = sum_j (w*W3 + b)
    const int unit = g - 1, l = unit >> 6, i = unit & 63;
    const float* Wl = Wm + (size_t)l * N * N * E * D;
    float4 a0 = {0,0,0,0}, a1 = {0,0,0,0}, a2 = {0,0,0,0}, a3 = {0,0,0,0};
    float4 bacc = {0,0,0,0};
    for (int j = 0; j < N; ++j) {
      const float v = ew[i * N + j];
      if (v > 0.f) {
        const float* Wp = Wl + (size_t)(i * N + j) * (E * D);
        f4acc(a0, f4ld(Wp + (0 * 256 + t) * 4));
        f4acc(a1, f4ld(Wp + (1 * 256 + t) * 4));
        f4acc(a2, f4ld(Wp + (2 * 256 + t) * 4));
        f4acc(a3, f4ld(Wp + (3 * 256 + t) * 4));
        if (t < 16) {
          const float4 w3 = f4ld(Wp + 2 * D * D + t * 4);
          const float4 bv = f4ld(bm + (((size_t)l * N + i) * N + j) * D + t * 4);
          bacc.x += v * w3.x + bv.x;
          bacc.y += v * w3.y + bv.y;
          bacc.z += v * w3.z + bv.z;
          bacc.w += v * w3.w + bv.w;
        }
      }
    }
    float* dst = sw1 + (size_t)unit * D * D;
    *(float4*)(dst + (0 * 256 + t) * 4) = a0;
    *(float4*)(dst + (1 * 256 + t) * 4) = a1;
    *(float4*)(dst + (2 * 256 + t) * 4) = a2;
    *(float4*)(dst + (3 * 256 + t) * 4) = a3;
    if (t < 16) *(float4*)(baseB + (size_t)unit * D + t * 4) = bacc;
  }
  gridbar(bar + 0);

  for (int l = 0; l < L; ++l) {
    const float* sin_p = (l == 0) ? x : s;
    const bool LAST = (l == L - 1);
    const float* Wl = Wm + (size_t)l * N * N * E * D;

    // ================= P1: per-edge K=64 GEMMs + per-node self GEMMs ======
    {
      float (*aT)[64] = (float(*)[64])pool;        // 16KB
      float* wLds = (float*)(pool + 16384);        // 16KB

      const int ne = *nedg;
      for (int u = g; u < ne + N; u += NBLK) {
        int jj;
        const float* wsrc;
        const float* basep;
        float* dst;
        if (u < ne) {
          const int ij = edgeIJ[u];
          jj = ij & 63;
          wsrc = Wl + (size_t)ij * (E * D) + D * D;      // W2 block
          dst = msg + (size_t)u * B * D;
          basep = nullptr;
        } else {
          const int i = u - ne;
          jj = i;
          wsrc = sw1 + ((size_t)l * N + i) * D * D;
          dst = selfmsg + (size_t)i * B * D;
          basep = baseB + ((size_t)l * N + i) * D;
        }
        // stage A^T
        {
          const int bb = t >> 2, q = t & 3;
          const float* ps = sin_p + ((size_t)(bb * N + jj)) * D + q * 16;
          const float4 v0 = f4ld(ps), v1 = f4ld(ps + 4),
                       v2 = f4ld(ps + 8), v3 = f4ld(ps + 12);
          const int k0 = q * 16;
          aT[k0 + 0][bb] = v0.x; aT[k0 + 1][bb] = v0.y;
          aT[k0 + 2][bb] = v0.z; aT[k0 + 3][bb] = v0.w;
          aT[k0 + 4][bb] = v1.x; aT[k0 + 5][bb] = v1.y;
          aT[k0 + 6][bb] = v1.z; aT[k0 + 7][bb] = v1.w;
          aT[k0 + 8][bb] = v2.x; aT[k0 + 9][bb] = v2.y;
          aT[k0 +10][bb] = v2.z; aT[k0 +11][bb] = v2.w;
          aT[k0 +12][bb] = v3.x; aT[k0 +13][bb] = v3.y;
          aT[k0 +14][bb] = v3.z; aT[k0 +15][bb] = v3.w;
        }
        // stage W (16KB, coalesced)
#pragma unroll
        for (int r = 0; r < 4; ++r)
          *(float4*)(wLds + (r * 256 + t) * 4) = f4ld(wsrc + (r * 256 + t) * 4);
        __syncthreads();

        const int td = t & 15, tb = t >> 4;
        float acc[4][4];
        if (basep) {
          const float4 bv = f4ld(basep + td * 4);
#pragma unroll
          for (int r = 0; r < 4; ++r) {
            acc[r][0] = bv.x; acc[r][1] = bv.y;
            acc[r][2] = bv.z; acc[r][3] = bv.w;
          }
        } else {
#pragma unroll
          for (int r = 0; r < 4; ++r)
#pragma unroll
            for (int c2 = 0; c2 < 4; ++c2) acc[r][c2] = 0.f;
        }
#pragma unroll 4
        for (int k = 0; k < D; ++k) {
          const float4 a = *(const float4*)&aT[k][tb * 4];
          const float4 wv = f4ld(wLds + k * D + td * 4);
          const float ar[4] = {a.x, a.y, a.z, a.w};
          const float wc[4] = {wv.x, wv.y, wv.z, wv.w};
#pragma unroll
          for (int r = 0; r < 4; ++r)
#pragma unroll
            for (int c2 = 0; c2 < 4; ++c2) acc[r][c2] += ar[r] * wc[c2];
        }
        float* mp = dst + ((size_t)(tb * 4)) * D + td * 4;
#pragma unroll
        for (int r = 0; r < 4; ++r)
          *(float4*)(mp + (size_t)r * D) =
              make_float4(acc[r][0], acc[r][1], acc[r][2], acc[r][3]);
        __syncthreads();  // LDS reuse by next unit
      }
    }
    gridbar(bar + 1 + 2 * l);

    // ================= P2: update MLP + residual + scan (+ readout) =======
    if (g < B) {
      const int b = g;
      const float* Wul = Wu + (size_t)l * 2 * D * D;
      const float* bul = bu + (size_t)l * D;

      float (*catT)[64] = (float(*)[64])pool;               // 32KB, persists
      float* wuL = (float*)(pool + 32768);                  // 32KB (GEMM only)
      // overlay of wuL after GEMM:
      float (*sb)[65] = (float(*)[65])(pool + 32768);       // 16640B
      uint4* nbrL = (uint4*)(pool + 49408);                 // 1KB
      float* degL = (float*)(pool + 50432);
      float* cwL  = (float*)(pool + 50688);
      int*   cntL = (int*)(pool + 50944);

      // ---- stage catT (sin + neighbor-summed msg) and wuL ----
      {
        const int ii = t >> 2, q = t & 3;
        const int cI = cntg[ii];
        const int rb = rowbase[ii];
        float4 a4[4];
#pragma unroll
        for (int kc = 0; kc < 4; ++kc)
          a4[kc] = f4ld(selfmsg + ((size_t)(ii * B + b)) * D + kc * 16 + q * 4);
        for (int e = 0; e < cI; ++e) {
          const float* pm = msg + ((size_t)(rb + e) * B + b) * D;
#pragma unroll
          for (int kc = 0; kc < 4; ++kc)
            f4acc(a4[kc], f4ld(pm + kc * 16 + q * 4));
        }
        const float* ps = sin_p + ((size_t)(b * N + ii)) * D;
#pragma unroll
        for (int kc = 0; kc < 4; ++kc) {
          const int k0 = kc * 16 + q * 4;
          const float4 v = f4ld(ps + k0);
          catT[k0 + 0][ii] = v.x; catT[k0 + 1][ii] = v.y;
          catT[k0 + 2][ii] = v.z; catT[k0 + 3][ii] = v.w;
          catT[D + k0 + 0][ii] = a4[kc].x; catT[D + k0 + 1][ii] = a4[kc].y;
          catT[D + k0 + 2][ii] = a4[kc].z; catT[D + k0 + 3][ii] = a4[kc].w;
        }
      }
#pragma unroll
      for (int r = 0; r < 8; ++r)   // Wu: 32KB coalesced vector staging
        *(float4*)(wuL + (r * 256 + t) * 4) = f4ld(Wul + (r * 256 + t) * 4);
      __syncthreads();

      // ---- upd GEMM, 4x4 register tile: rows i=4tb.., cols d=4td.. ----
      const int td = t & 15, tb = t >> 4;
      float acc[4][4];
      {
        const float4 bv = f4ld(bul + td * 4);
#pragma unroll
        for (int r = 0; r < 4; ++r) {
          acc[r][0] = bv.x; acc[r][1] = bv.y;
          acc[r][2] = bv.z; acc[r][3] = bv.w;
        }
      }
#pragma unroll 4
      for (int k = 0; k < 2 * D; ++k) {
        const float4 a = *(const float4*)&catT[k][tb * 4];
        const float4 wv = f4ld(wuL + k * D + td * 4);
        const float ar[4] = {a.x, a.y, a.z, a.w};
        const float wc[4] = {wv.x, wv.y, wv.z, wv.w};
#pragma unroll
        for (int r = 0; r < 4; ++r)
#pragma unroll
          for (int c2 = 0; c2 < 4; ++c2) acc[r][c2] += ar[r] * wc[c2];
      }
      __syncthreads();  // all wuL reads done; safe to overlay sb/tables

      // residual mix into sb (s_old[i][d] = catT[d][i], catT intact)
#pragma unroll
      for (int r = 0; r < 4; ++r)
#pragma unroll
        for (int c2 = 0; c2 < 4; ++c2)
          sb[tb * 4 + r][td * 4 + c2] =
              0.9f * acc[r][c2] + 0.1f * catT[td * 4 + c2][tb * 4 + r];
      if (t < N) {
        nbrL[t] = nbr4[t];
        degL[t] = degf[t];
        cntL[t] = cntg[t];
        if (LAST) cwL[t] = cwg[t];
      }
      __syncthreads();

      // ---- sequential node scan; lane d owns column d (wave 0) ----
      if (t < N) {
        const int d = t;
        uint4 w = nbrL[0];
        int c = cntL[0];
        float dg = degL[0];
        for (int ii = 0; ii < N; ++ii) {
          uint4 wn = w; int cn = c; float dgn = dg;
          if (ii < N - 1) { wn = nbrL[ii + 1]; cn = cntL[ii + 1]; dgn = degL[ii + 1]; }
          const unsigned wd[4] = {w.x, w.y, w.z, w.w};
          float nb = 0.0f;
#pragma unroll
          for (int q = 0; q < 8; ++q) {
            const int idx = (int)((wd[q >> 2] >> ((q & 3) * 8)) & 63u);
            const float v = sb[idx][d];
            nb += (q < c) ? v : 0.0f;
          }
          if (c > 8) {
#pragma unroll
            for (int q = 8; q < 16; ++q) {
              const int idx = (int)((wd[q >> 2] >> ((q & 3) * 8)) & 63u);
              const float v = sb[idx][d];
              nb += (q < c) ? v : 0.0f;
            }
            for (int q = 16; q < c; ++q) nb += sb[nfull[ii * N + q]][d];
          }
          const float avg = nb / fmaxf(dg, 1.0f);
          const float cur = sb[ii][d];
          sb[ii][d] = (dg > 0.0f) ? (0.95f * cur + 0.05f * avg) : cur;
          w = wn; c = cn; dg = dgn;
        }
        if (LAST) {
          float gg = 0.0f;
          for (int i2 = 0; i2 < N; ++i2) gg += cwL[i2] * sb[i2][d];
          float o = bo[d];
          for (int k2 = 0; k2 < D; ++k2) o += __shfl(gg, k2, 64) * Wo[k2 * D + d];
          out[(size_t)b * D + d] = o;
        }
      }

      if (!LAST) {
        __syncthreads();
        const int ii = t >> 2, q = t & 3;
        float* ps = s + ((size_t)(b * N + ii)) * D;
#pragma unroll
        for (int kc = 0; kc < 4; ++kc) {
          const int k0 = kc * 16 + q * 4;
          float4 v;
          v.x = sb[ii][k0 + 0]; v.y = sb[ii][k0 + 1];
          v.z = sb[ii][k0 + 2]; v.w = sb[ii][k0 + 3];
          *(float4*)(ps + k0) = v;
        }
      }
    }
    if (l < L - 1) gridbar(bar + 2 + 2 * l);
  }
}

}  // namespace

extern "C" void kernel_launch(void* const* d_in, const int* in_sizes, int n_in,
                              void* d_out, int out_size, void* d_ws, size_t ws_size,
                              hipStream_t stream)
{
  const float* x  = (const float*)d_in[0];
  const float* ew = (const float*)d_in[1];
  const float* Wm = (const float*)d_in[2];
  const float* bm = (const float*)d_in[3];
  const float* Wu = (const float*)d_in[4];
  const float* bu = (const float*)d_in[5];
  const float* Wo = (const float*)d_in[6];
  const float* bo = (const float*)d_in[7];
  float* out = (float*)d_out;

  int L = in_sizes[2] / (N * N * E * D);  // = 3
  if (L > LMAX) L = LMAX;

  hipMemsetAsync(d_ws, 0, 256, stream);  // zero grid-barrier counters
  k_fused<<<NBLK, 256, 0, stream>>>(x, ew, Wm, bm, Wu, bu, Wo, bo, out,
                                    (char*)d_ws, L);
}

// Round 10
// 204.972 us; speedup vs baseline: 2.0156x; 1.2827x over previous
//
#include <hip/hip_runtime.h>

namespace {

constexpr int B = 64, N = 64, D = 64, E = 2 * D + 1;  // E = 129
constexpr int NBLK = 256;   // exactly 1 block per CU -> guaranteed co-resident
constexpr int LMAX = 3;
constexpr size_t MAXSLOT = 1024;

__device__ __forceinline__ float4 f4ld(const float* p) { return *(const float4*)p; }
__device__ __forceinline__ void f4acc(float4& a, const float4 b) {
  a.x += b.x; a.y += b.y; a.z += b.z; a.w += b.w;
}

// Two-level tree grid barrier. Arrivals spread over 8 cachelines (32 RMWs
// each, parallel) -> ~1.4us instead of 256 serialized RMWs (~11.5us).
// Each barrier instance uses its own counter set (144 uints), zeroed by the
// memset node each launch.
__device__ __forceinline__ void gridbar(unsigned* set) {
  __syncthreads();
  if (threadIdx.x == 0) {
    const int g = blockIdx.x;
    unsigned* leaf = set + (size_t)(g & 7) * 16;   // 64B apart
    unsigned* root = set + 8 * 16;
    __threadfence();  // release: make prior writes device-visible
    __hip_atomic_fetch_add(leaf, 1u, __ATOMIC_RELAXED, __HIP_MEMORY_SCOPE_AGENT);
    if (g < 8) {
      while (__hip_atomic_load(leaf, __ATOMIC_RELAXED, __HIP_MEMORY_SCOPE_AGENT)
             < (unsigned)(NBLK / 8))
        __builtin_amdgcn_s_sleep(2);
      __threadfence();
      __hip_atomic_fetch_add(root, 1u, __ATOMIC_RELAXED, __HIP_MEMORY_SCOPE_AGENT);
    }
    while (__hip_atomic_load(root, __ATOMIC_RELAXED, __HIP_MEMORY_SCOPE_AGENT) < 8u)
      __builtin_amdgcn_s_sleep(2);
    __threadfence();  // acquire
  }
  __syncthreads();
}

// LDS layout (bytes). Scratch [0,48K): P1 aT(16K)+wLds(16K); P2 catT(32K)+
// wuC(16K); sb overlays catT after residual. Persistent tables at 48K+.
constexpr int OF_WU    = 32768;
constexpr int OF_TB    = 49152;
constexpr int OF_NBR4  = OF_TB;           // 1024
constexpr int OF_DEG   = OF_TB + 1024;    // 256
constexpr int OF_CW    = OF_TB + 1280;    // 256
constexpr int OF_CNT   = OF_TB + 1536;    // 256
constexpr int OF_RB    = OF_TB + 1792;    // 256
constexpr int OF_BTMP  = OF_TB + 2048;    // 256
constexpr int OF_NE    = OF_TB + 2304;    // 16
constexpr int OF_EI    = OF_TB + 2320;    // 2048
constexpr int OF_NFULL = OF_TB + 4368;    // 4096 -> 57616
constexpr int POOLSZ   = 57856;

__global__ __launch_bounds__(256) void k_fused(
    const float* __restrict__ x,   // [B][N][D]
    const float* __restrict__ ew,  // [N][N]
    const float* __restrict__ Wm,  // [L][N][N][E][D]
    const float* __restrict__ bm,  // [L][N][N][D]
    const float* __restrict__ Wu,  // [L][2D][D]
    const float* __restrict__ bu,  // [L][D]
    const float* __restrict__ Wo,  // [D][D]
    const float* __restrict__ bo,  // [D]
    float* __restrict__ out,       // [B][D]
    char* __restrict__ ws, int L)
{
  unsigned* bar = (unsigned*)ws;            // 5 sets x 144 uints, memset 4KB
  char* p = ws + 4096;
  float* s       = (float*)p; p += (size_t)B * N * D * 4;
  float* selfmsg = (float*)p; p += (size_t)N * B * D * 4;
  float* msg     = (float*)p; p += MAXSLOT * (size_t)B * D * 4;
  float* sw1     = (float*)p; p += (size_t)(LMAX - 1) * N * D * D * 4;
  float* baseB   = (float*)p;               // [LMAX-1][N][D]

  __shared__ __align__(16) char pool[POOLSZ];
  float (*aT)[64] = (float(*)[64])pool;                 // 16KB
  float* wLds  = (float*)(pool + 16384);                // 16KB
  uint4* nbr4L = (uint4*)(pool + OF_NBR4);
  float* degL  = (float*)(pool + OF_DEG);
  float* cwL   = (float*)(pool + OF_CW);
  int*   cntL  = (int*)(pool + OF_CNT);
  int*   rbL   = (int*)(pool + OF_RB);
  float* baseTmp = (float*)(pool + OF_BTMP);
  int*   neL   = (int*)(pool + OF_NE);
  unsigned short* eiL = (unsigned short*)(pool + OF_EI);
  unsigned char* nfullL = (unsigned char*)(pool + OF_NFULL);

  const int g = blockIdx.x, t = threadIdx.x;

  // ---- prep: redundant per block, zero cross-block deps, no barrier ----
  {
    float* ewL = (float*)pool;  // 16KB overlay on aT
#pragma unroll
    for (int r = 0; r < 4; ++r)
      ((float4*)ewL)[r * 256 + t] = ((const float4*)ew)[r * 256 + t];
    __syncthreads();
    if (t < 64) {
      float rowsum = 0.f; int rc = 0;
      for (int j = 0; j < N; ++j) {
        const float v = ewL[t * N + j];
        rowsum += v; rc += (v > 0.f) ? 1 : 0;
      }
      int pre = rc;
#pragma unroll
      for (int off = 1; off < 64; off <<= 1) {
        int v = __shfl_up(pre, off, 64);
        if (t >= off) pre += v;
      }
      const int base = pre - rc;
      rbL[t] = base;
      unsigned long long lo = 0ull, hi = 0ull; int c = 0;
      for (int j = 0; j < N; ++j) {
        const float v = ewL[t * N + j];
        if (v > 0.f) {
          eiL[base + c] = (unsigned short)((t << 6) | j);
          if (c < 8)       lo |= (unsigned long long)j << (c * 8);
          else if (c < 16) hi |= (unsigned long long)j << ((c - 8) * 8);
          nfullL[t * 64 + c] = (unsigned char)j;
          ++c;
        }
      }
      uint4 w4;
      w4.x = (unsigned)lo; w4.y = (unsigned)(lo >> 32);
      w4.z = (unsigned)hi; w4.w = (unsigned)(hi >> 32);
      nbr4L[t] = w4; cntL[t] = c; degL[t] = (float)c;
      float tot = rowsum;
#pragma unroll
      for (int off = 32; off >= 1; off >>= 1) tot += __shfl_xor(tot, off, 64);
      cwL[t] = rowsum / (tot + 1e-8f);
      if (t == 63) *neL = base + rc;
    }
    __syncthreads();
  }
  const int ne = *neL;

  for (int l = 0; l < L; ++l) {
    const float* scur = (l == 0) ? x : s;
    const bool LAST = (l == L - 1);

    // ===== P1: edge GEMMs (K=64) + self GEMMs + (l==0) sw1 precompute =====
    {
      const int U = ne + N + ((l == 0) ? (L - 1) * N : 0);
      for (int u = g; u < U; u += NBLK) {
        if (u >= ne + N) {
          // pre-unit: sw1/base for layer lt+1 (weights only; no s dep)
          const int v2 = u - ne - N, lt = v2 >> 6, i = v2 & 63;
          float4 a0 = {0,0,0,0}, a1 = {0,0,0,0}, a2 = {0,0,0,0}, a3 = {0,0,0,0};
          float4 bacc = {0,0,0,0};
          const int ci = cntL[i];
          for (int c2 = 0; c2 < ci; ++c2) {
            const int j2 = nfullL[i * 64 + c2];
            const float* Wp = Wm + ((size_t)(((lt + 1) * N + i) * N + j2)) * (E * D);
            f4acc(a0, f4ld(Wp + (0 * 256 + t) * 4));
            f4acc(a1, f4ld(Wp + (1 * 256 + t) * 4));
            f4acc(a2, f4ld(Wp + (2 * 256 + t) * 4));
            f4acc(a3, f4ld(Wp + (3 * 256 + t) * 4));
            if (t < 16) {
              const float w = ew[i * N + j2];
              const float4 w3 = f4ld(Wp + 2 * D * D + t * 4);
              const float4 bv = f4ld(bm + (((size_t)(lt + 1) * N + i) * N + j2) * D + t * 4);
              bacc.x += w * w3.x + bv.x; bacc.y += w * w3.y + bv.y;
              bacc.z += w * w3.z + bv.z; bacc.w += w * w3.w + bv.w;
            }
          }
          float* dstw = sw1 + ((size_t)lt * N + i) * D * D;
          *(float4*)(dstw + (0 * 256 + t) * 4) = a0;
          *(float4*)(dstw + (1 * 256 + t) * 4) = a1;
          *(float4*)(dstw + (2 * 256 + t) * 4) = a2;
          *(float4*)(dstw + (3 * 256 + t) * 4) = a3;
          if (t < 16) *(float4*)(baseB + ((size_t)lt * N + i) * D + t * 4) = bacc;
          continue;
        }
        const bool self = (u >= ne);
        int i, jj; float* dst;
        if (self) { i = u - ne; jj = i; dst = selfmsg + (size_t)i * B * D; }
        else {
          const int e = eiL[u]; i = e >> 6; jj = e & 63;
          dst = msg + (size_t)u * B * D;
        }
        // stage A^T from scur[:, jj]
        {
          const int bb = t >> 2, q = t & 3;
          const float* ps = scur + ((size_t)(bb * N + jj)) * D + q * 16;
          const float4 v0 = f4ld(ps), v1 = f4ld(ps + 4),
                       v2 = f4ld(ps + 8), v3 = f4ld(ps + 12);
          const int k0 = q * 16;
          aT[k0 + 0][bb] = v0.x; aT[k0 + 1][bb] = v0.y;
          aT[k0 + 2][bb] = v0.z; aT[k0 + 3][bb] = v0.w;
          aT[k0 + 4][bb] = v1.x; aT[k0 + 5][bb] = v1.y;
          aT[k0 + 6][bb] = v1.z; aT[k0 + 7][bb] = v1.w;
          aT[k0 + 8][bb] = v2.x; aT[k0 + 9][bb] = v2.y;
          aT[k0 +10][bb] = v2.z; aT[k0 +11][bb] = v2.w;
          aT[k0 +12][bb] = v3.x; aT[k0 +13][bb] = v3.y;
          aT[k0 +14][bb] = v3.z; aT[k0 +15][bb] = v3.w;
        }
        // stage W (16KB) + base
        if (!self) {
          const int e = eiL[u];
          const float* wsrc = Wm + ((size_t)((l * N + (e >> 6)) * N + (e & 63))) * (E * D) + D * D;
#pragma unroll
          for (int r = 0; r < 4; ++r)
            *(float4*)(wLds + (r * 256 + t) * 4) = f4ld(wsrc + (r * 256 + t) * 4);
        } else if (l > 0) {
          const float* wsrc = sw1 + ((size_t)(l - 1) * N + i) * D * D;
#pragma unroll
          for (int r = 0; r < 4; ++r)
            *(float4*)(wLds + (r * 256 + t) * 4) = f4ld(wsrc + (r * 256 + t) * 4);
          if (t < 16)
            *(float4*)(baseTmp + t * 4) = f4ld(baseB + ((size_t)(l - 1) * N + i) * D + t * 4);
        } else {
          // l==0 self: inline W1-sum over neighbors + base
          float4 a0 = {0,0,0,0}, a1 = {0,0,0,0}, a2 = {0,0,0,0}, a3 = {0,0,0,0};
          float4 bacc = {0,0,0,0};
          const int ci = cntL[i];
          for (int c2 = 0; c2 < ci; ++c2) {
            const int j2 = nfullL[i * 64 + c2];
            const float* Wp = Wm + ((size_t)(i * N + j2)) * (E * D);
            f4acc(a0, f4ld(Wp + (0 * 256 + t) * 4));
            f4acc(a1, f4ld(Wp + (1 * 256 + t) * 4));
            f4acc(a2, f4ld(Wp + (2 * 256 + t) * 4));
            f4acc(a3, f4ld(Wp + (3 * 256 + t) * 4));
            if (t < 16) {
              const float w = ew[i * N + j2];
              const float4 w3 = f4ld(Wp + 2 * D * D + t * 4);
              const float4 bv = f4ld(bm + ((size_t)(i * N + j2)) * D + t * 4);
              bacc.x += w * w3.x + bv.x; bacc.y += w * w3.y + bv.y;
              bacc.z += w * w3.z + bv.z; bacc.w += w * w3.w + bv.w;
            }
          }
          *(float4*)(wLds + (0 * 256 + t) * 4) = a0;
          *(float4*)(wLds + (1 * 256 + t) * 4) = a1;
          *(float4*)(wLds + (2 * 256 + t) * 4) = a2;
          *(float4*)(wLds + (3 * 256 + t) * 4) = a3;
          if (t < 16) *(float4*)(baseTmp + t * 4) = bacc;
        }
        __syncthreads();

        const int td = t & 15, tb = t >> 4;
        float acc[4][4];
        if (self) {
          const float4 bv = f4ld(baseTmp + td * 4);
#pragma unroll
          for (int r = 0; r < 4; ++r) {
            acc[r][0] = bv.x; acc[r][1] = bv.y;
            acc[r][2] = bv.z; acc[r][3] = bv.w;
          }
        } else {
#pragma unroll
          for (int r = 0; r < 4; ++r)
#pragma unroll
            for (int c2 = 0; c2 < 4; ++c2) acc[r][c2] = 0.f;
        }
#pragma unroll 4
        for (int k = 0; k < D; ++k) {
          const float4 a  = *(const float4*)&aT[k][tb * 4];
          const float4 wv = f4ld(wLds + k * D + td * 4);
          const float ar[4] = {a.x, a.y, a.z, a.w};
          const float wc[4] = {wv.x, wv.y, wv.z, wv.w};
#pragma unroll
          for (int r = 0; r < 4; ++r)
#pragma unroll
            for (int c2 = 0; c2 < 4; ++c2) acc[r][c2] += ar[r] * wc[c2];
        }
        float* mp = dst + (size_t)(tb * 4) * D + td * 4;
#pragma unroll
        for (int r = 0; r < 4; ++r)
          *(float4*)(mp + (size_t)r * D) =
              make_float4(acc[r][0], acc[r][1], acc[r][2], acc[r][3]);
        __syncthreads();  // LDS reuse by next unit
      }
    }
    gridbar(bar + (size_t)(2 * l) * 144);

    // ===== P2: update MLP + residual + scan (+ readout), blocks 0..63 =====
    if (g < B) {
      const int b = g;
      const float* Wul = Wu + (size_t)l * 2 * D * D;
      const float* bul = bu + (size_t)l * D;
      float (*catT)[64] = (float(*)[64])pool;          // 32KB
      float* wuC = (float*)(pool + OF_WU);             // 16KB chunk

      {
        const int ii = t >> 2, q = t & 3;
        const int cI = cntL[ii], rb = rbL[ii];
        float4 a4[4];
#pragma unroll
        for (int kc = 0; kc < 4; ++kc)
          a4[kc] = f4ld(selfmsg + ((size_t)(ii * B + b)) * D + kc * 16 + q * 4);
        for (int e = 0; e < cI; ++e) {
          const float* pm = msg + ((size_t)(rb + e) * B + b) * D;
#pragma unroll
          for (int kc = 0; kc < 4; ++kc) f4acc(a4[kc], f4ld(pm + kc * 16 + q * 4));
        }
        const float* ps = scur + ((size_t)(b * N + ii)) * D;
#pragma unroll
        for (int kc = 0; kc < 4; ++kc) {
          const int k0 = kc * 16 + q * 4;
          const float4 v = f4ld(ps + k0);
          catT[k0 + 0][ii] = v.x; catT[k0 + 1][ii] = v.y;
          catT[k0 + 2][ii] = v.z; catT[k0 + 3][ii] = v.w;
          catT[D + k0 + 0][ii] = a4[kc].x; catT[D + k0 + 1][ii] = a4[kc].y;
          catT[D + k0 + 2][ii] = a4[kc].z; catT[D + k0 + 3][ii] = a4[kc].w;
        }
      }
#pragma unroll
      for (int r = 0; r < 4; ++r)
        *(float4*)(wuC + (r * 256 + t) * 4) = f4ld(Wul + (r * 256 + t) * 4);
      __syncthreads();

      const int td = t & 15, tb = t >> 4;
      float acc[4][4];
      {
        const float4 bv = f4ld(bul + td * 4);
#pragma unroll
        for (int r = 0; r < 4; ++r) {
          acc[r][0] = bv.x; acc[r][1] = bv.y;
          acc[r][2] = bv.z; acc[r][3] = bv.w;
        }
      }
#pragma unroll 4
      for (int k = 0; k < 64; ++k) {
        const float4 a  = *(const float4*)&catT[k][tb * 4];
        const float4 wv = f4ld(wuC + k * D + td * 4);
        const float ar[4] = {a.x, a.y, a.z, a.w};
        const float wc[4] = {wv.x, wv.y, wv.z, wv.w};
#pragma unroll
        for (int r = 0; r < 4; ++r)
#pragma unroll
          for (int c2 = 0; c2 < 4; ++c2) acc[r][c2] += ar[r] * wc[c2];
      }
      __syncthreads();
#pragma unroll
      for (int r = 0; r < 4; ++r)
        *(float4*)(wuC + (r * 256 + t) * 4) = f4ld(Wul + 64 * D + (r * 256 + t) * 4);
      __syncthreads();
#pragma unroll 4
      for (int k = 0; k < 64; ++k) {
        const float4 a  = *(const float4*)&catT[64 + k][tb * 4];
        const float4 wv = f4ld(wuC + k * D + td * 4);
        const float ar[4] = {a.x, a.y, a.z, a.w};
        const float wc[4] = {wv.x, wv.y, wv.z, wv.w};
#pragma unroll
        for (int r = 0; r < 4; ++r)
#pragma unroll
          for (int c2 = 0; c2 < 4; ++c2) acc[r][c2] += ar[r] * wc[c2];
      }
      // residual into registers (reads catT), then overlay sb on catT
#pragma unroll
      for (int r = 0; r < 4; ++r)
#pragma unroll
        for (int c2 = 0; c2 < 4; ++c2)
          acc[r][c2] = 0.9f * acc[r][c2] + 0.1f * catT[td * 4 + c2][tb * 4 + r];
      __syncthreads();
      float (*sb)[65] = (float(*)[65])pool;
#pragma unroll
      for (int r = 0; r < 4; ++r)
#pragma unroll
        for (int c2 = 0; c2 < 4; ++c2)
          sb[tb * 4 + r][td * 4 + c2] = acc[r][c2];
      __syncthreads();

      // sequential node scan; lane d owns column d (wave 0)
      if (t < 64) {
        const int d = t;
        uint4 w = nbr4L[0];
        int c = cntL[0];
        float dg = degL[0];
        for (int ii = 0; ii < N; ++ii) {
          uint4 wn = w; int cn = c; float dgn = dg;
          if (ii < N - 1) { wn = nbr4L[ii + 1]; cn = cntL[ii + 1]; dgn = degL[ii + 1]; }
          const unsigned wd[4] = {w.x, w.y, w.z, w.w};
          float nb = 0.0f;
#pragma unroll
          for (int q = 0; q < 8; ++q) {
            const int idx = (int)((wd[q >> 2] >> ((q & 3) * 8)) & 63u);
            const float v = sb[idx][d];
            nb += (q < c) ? v : 0.0f;
          }
          if (c > 8) {
#pragma unroll
            for (int q = 8; q < 16; ++q) {
              const int idx = (int)((wd[q >> 2] >> ((q & 3) * 8)) & 63u);
              const float v = sb[idx][d];
              nb += (q < c) ? v : 0.0f;
            }
            for (int q = 16; q < c; ++q) nb += sb[nfullL[ii * 64 + q]][d];
          }
          const float avg = nb / fmaxf(dg, 1.0f);
          const float cur = sb[ii][d];
          sb[ii][d] = (dg > 0.0f) ? (0.95f * cur + 0.05f * avg) : cur;
          w = wn; c = cn; dg = dgn;
        }
        if (LAST) {
          float gg = 0.0f;
          for (int i2 = 0; i2 < N; ++i2) gg += cwL[i2] * sb[i2][d];
          float o = bo[d];
          for (int k2 = 0; k2 < D; ++k2) o += __shfl(gg, k2, 64) * Wo[k2 * D + d];
          out[(size_t)b * D + d] = o;
        }
      }
      if (!LAST) {
        __syncthreads();
        const int ii = t >> 2, q = t & 3;
        float* ps = s + ((size_t)(b * N + ii)) * D;
#pragma unroll
        for (int kc = 0; kc < 4; ++kc) {
          const int k0 = kc * 16 + q * 4;
          float4 v;
          v.x = sb[ii][k0 + 0]; v.y = sb[ii][k0 + 1];
          v.z = sb[ii][k0 + 2]; v.w = sb[ii][k0 + 3];
          *(float4*)(ps + k0) = v;
        }
      }
    }
    if (l < L - 1) gridbar(bar + (size_t)(2 * l + 1) * 144);
  }
}

}  // namespace

extern "C" void kernel_launch(void* const* d_in, const int* in_sizes, int n_in,
                              void* d_out, int out_size, void* d_ws, size_t ws_size,
                              hipStream_t stream)
{
  const float* x  = (const float*)d_in[0];
  const float* ew = (const float*)d_in[1];
  const float* Wm = (const float*)d_in[2];
  const float* bm = (const float*)d_in[3];
  const float* Wu = (const float*)d_in[4];
  const float* bu = (const float*)d_in[5];
  const float* Wo = (const float*)d_in[6];
  const float* bo = (const float*)d_in[7];
  float* out = (float*)d_out;

  int L = in_sizes[2] / (N * N * E * D);  // = 3
  if (L > LMAX) L = LMAX;

  hipMemsetAsync(d_ws, 0, 4096, stream);  // zero all barrier counter sets
  k_fused<<<NBLK, 256, 0, stream>>>(x, ew, Wm, bm, Wu, bu, Wo, bo, out,
                                    (char*)d_ws, L);
}

// Round 11
// 201.942 us; speedup vs baseline: 2.0458x; 1.0150x over previous
//
#include <hip/hip_runtime.h>

namespace {

constexpr int B = 64, N = 64, D = 64, E = 2 * D + 1;  // E = 129
constexpr int NBLK = 256;   // 1 block/CU
constexpr int NTH  = 512;   // 8 waves/CU
constexpr int LMAX = 3;
constexpr size_t MAXSLOT = 1024;

__device__ __forceinline__ float4 f4ld(const float* p) { return *(const float4*)p; }
__device__ __forceinline__ void f4acc(float4& a, const float4 b) {
  a.x += b.x; a.y += b.y; a.z += b.z; a.w += b.w;
}

// Two-level tree grid barrier (verified r10). Arrivals spread over 8
// cachelines; root polled with relaxed agent-scope loads.
__device__ __forceinline__ void gridbar(unsigned* set) {
  __syncthreads();
  if (threadIdx.x == 0) {
    const int g = blockIdx.x;
    unsigned* leaf = set + (size_t)(g & 7) * 16;   // 64B apart
    unsigned* root = set + 8 * 16;
    __threadfence();  // release
    __hip_atomic_fetch_add(leaf, 1u, __ATOMIC_RELAXED, __HIP_MEMORY_SCOPE_AGENT);
    if (g < 8) {
      while (__hip_atomic_load(leaf, __ATOMIC_RELAXED, __HIP_MEMORY_SCOPE_AGENT)
             < (unsigned)(NBLK / 8))
        __builtin_amdgcn_s_sleep(2);
      __threadfence();
      __hip_atomic_fetch_add(root, 1u, __ATOMIC_RELAXED, __HIP_MEMORY_SCOPE_AGENT);
    }
    while (__hip_atomic_load(root, __ATOMIC_RELAXED, __HIP_MEMORY_SCOPE_AGENT) < 8u)
      __builtin_amdgcn_s_sleep(2);
    __threadfence();  // acquire
  }
  __syncthreads();
}

// LDS layout (bytes). Scratch [0,48K): P1 aT(16K)+wLds(16K);
// P2 catT(32K)+wuC(16K at 32K); sb overlays catT. Tables at 48K+.
constexpr int OF_WU    = 32768;
constexpr int OF_TB    = 49152;
constexpr int OF_NBR4  = OF_TB;           // 1024
constexpr int OF_DEG   = OF_TB + 1024;
constexpr int OF_CW    = OF_TB + 1280;
constexpr int OF_CNT   = OF_TB + 1536;
constexpr int OF_RB    = OF_TB + 1792;
constexpr int OF_BTMP  = OF_TB + 2048;
constexpr int OF_NE    = OF_TB + 2304;
constexpr int OF_EI    = OF_TB + 2320;    // 2048
constexpr int OF_NFULL = OF_TB + 4368;    // 4096
constexpr int POOLSZ   = 57856;

__global__ __launch_bounds__(NTH) void k_fused(
    const float* __restrict__ x,   // [B][N][D]
    const float* __restrict__ ew,  // [N][N]
    const float* __restrict__ Wm,  // [L][N][N][E][D]
    const float* __restrict__ bm,  // [L][N][N][D]
    const float* __restrict__ Wu,  // [L][2D][D]
    const float* __restrict__ bu,  // [L][D]
    const float* __restrict__ Wo,  // [D][D]
    const float* __restrict__ bo,  // [D]
    float* __restrict__ out,       // [B][D]
    char* __restrict__ ws, int L)
{
  unsigned* bar = (unsigned*)ws;            // 5 sets x 144 uints (memset 4KB)
  char* p = ws + 4096;
  float* s       = (float*)p; p += (size_t)B * N * D * 4;
  float* selfmsg = (float*)p; p += (size_t)N * B * D * 4;
  float* msg     = (float*)p; p += MAXSLOT * (size_t)B * D * 4;
  float* sw1     = (float*)p; p += (size_t)(LMAX - 1) * N * D * D * 4;
  float* baseB   = (float*)p;               // [LMAX-1][N][D]

  __shared__ __align__(16) char pool[POOLSZ];
  float (*aT)[64] = (float(*)[64])pool;                 // 16KB
  float* wLds  = (float*)(pool + 16384);                // 16KB
  uint4* nbr4L = (uint4*)(pool + OF_NBR4);
  float* degL  = (float*)(pool + OF_DEG);
  float* cwL   = (float*)(pool + OF_CW);
  int*   cntL  = (int*)(pool + OF_CNT);
  int*   rbL   = (int*)(pool + OF_RB);
  float* baseTmp = (float*)(pool + OF_BTMP);
  int*   neL   = (int*)(pool + OF_NE);
  unsigned short* eiL = (unsigned short*)(pool + OF_EI);
  unsigned char* nfullL = (unsigned char*)(pool + OF_NFULL);

  const int g = blockIdx.x, t = threadIdx.x;

  // ---- prep: redundant per block, no cross-block deps ----
  {
    float* ewL = (float*)pool;  // overlay on aT
#pragma unroll
    for (int r = 0; r < 2; ++r)
      ((float4*)ewL)[r * NTH + t] = ((const float4*)ew)[r * NTH + t];
    __syncthreads();
    if (t < 64) {
      float rowsum = 0.f; int rc = 0;
      for (int j = 0; j < N; ++j) {
        const float v = ewL[t * N + j];
        rowsum += v; rc += (v > 0.f) ? 1 : 0;
      }
      int pre = rc;
#pragma unroll
      for (int off = 1; off < 64; off <<= 1) {
        int v = __shfl_up(pre, off, 64);
        if (t >= off) pre += v;
      }
      const int base = pre - rc;
      rbL[t] = base;
      unsigned long long lo = 0ull, hi = 0ull; int c = 0;
      for (int j = 0; j < N; ++j) {
        const float v = ewL[t * N + j];
        if (v > 0.f) {
          eiL[base + c] = (unsigned short)((t << 6) | j);
          if (c < 8)       lo |= (unsigned long long)j << (c * 8);
          else if (c < 16) hi |= (unsigned long long)j << ((c - 8) * 8);
          nfullL[t * 64 + c] = (unsigned char)j;
          ++c;
        }
      }
      uint4 w4;
      w4.x = (unsigned)lo; w4.y = (unsigned)(lo >> 32);
      w4.z = (unsigned)hi; w4.w = (unsigned)(hi >> 32);
      nbr4L[t] = w4; cntL[t] = c; degL[t] = (float)c;
      float tot = rowsum;
#pragma unroll
      for (int off = 32; off >= 1; off >>= 1) tot += __shfl_xor(tot, off, 64);
      cwL[t] = rowsum / (tot + 1e-8f);
      if (t == 63) *neL = base + rc;
    }
    __syncthreads();
  }
  const int ne = *neL;

  for (int l = 0; l < L; ++l) {
    const float* scur = (l == 0) ? x : s;
    const bool LAST = (l == L - 1);

    // ===== P1: edge GEMMs (K=64) + self GEMMs, 512 threads/unit =====
    {
      const int U = ne + N;
      for (int u = g; u < U; u += NBLK) {
        const bool self = (u >= ne);
        int i, jj; float* dst;
        if (self) { i = u - ne; jj = i; dst = selfmsg + (size_t)i * B * D; }
        else {
          const int e = eiL[u]; i = e >> 6; jj = e & 63;
          dst = msg + (size_t)u * B * D;
        }
        // stage A^T from scur[:, jj]: thread (bb,q) handles 8 k-values
        {
          const int bb = t >> 3, q = t & 7;
          const float* ps = scur + ((size_t)(bb * N + jj)) * D + q * 8;
          const float4 v0 = f4ld(ps), v1 = f4ld(ps + 4);
          const int k0 = q * 8;
          aT[k0 + 0][bb] = v0.x; aT[k0 + 1][bb] = v0.y;
          aT[k0 + 2][bb] = v0.z; aT[k0 + 3][bb] = v0.w;
          aT[k0 + 4][bb] = v1.x; aT[k0 + 5][bb] = v1.y;
          aT[k0 + 6][bb] = v1.z; aT[k0 + 7][bb] = v1.w;
        }
        // stage W (16KB) + base
        if (!self) {
          const int e = eiL[u];
          const float* wsrc = Wm + ((size_t)((l * N + (e >> 6)) * N + (e & 63))) * (E * D) + D * D;
#pragma unroll
          for (int r = 0; r < 2; ++r)
            *(float4*)(wLds + (r * NTH + t) * 4) = f4ld(wsrc + (r * NTH + t) * 4);
        } else if (l > 0) {
          const float* wsrc = sw1 + ((size_t)(l - 1) * N + i) * D * D;
#pragma unroll
          for (int r = 0; r < 2; ++r)
            *(float4*)(wLds + (r * NTH + t) * 4) = f4ld(wsrc + (r * NTH + t) * 4);
          if (t < 16)
            *(float4*)(baseTmp + t * 4) = f4ld(baseB + ((size_t)(l - 1) * N + i) * D + t * 4);
        } else {
          // l==0 self: inline W1-sum over neighbors + base
          float4 a0 = {0,0,0,0}, a1 = {0,0,0,0};
          float4 bacc = {0,0,0,0};
          const int ci = cntL[i];
          for (int c2 = 0; c2 < ci; ++c2) {
            const int j2 = nfullL[i * 64 + c2];
            const float* Wp = Wm + ((size_t)(i * N + j2)) * (E * D);
            f4acc(a0, f4ld(Wp + (0 * NTH + t) * 4));
            f4acc(a1, f4ld(Wp + (1 * NTH + t) * 4));
            if (t < 16) {
              const float w = ew[i * N + j2];
              const float4 w3 = f4ld(Wp + 2 * D * D + t * 4);
              const float4 bv = f4ld(bm + ((size_t)(i * N + j2)) * D + t * 4);
              bacc.x += w * w3.x + bv.x; bacc.y += w * w3.y + bv.y;
              bacc.z += w * w3.z + bv.z; bacc.w += w * w3.w + bv.w;
            }
          }
          *(float4*)(wLds + (0 * NTH + t) * 4) = a0;
          *(float4*)(wLds + (1 * NTH + t) * 4) = a1;
          if (t < 16) *(float4*)(baseTmp + t * 4) = bacc;
        }
        __syncthreads();

        // 2x4 register tile: rows b = 2*tr..+2, cols d = 4*td..+4
        const int td = t & 15, tr = t >> 4;
        float acc[2][4];
        if (self) {
          const float4 bv = f4ld(baseTmp + td * 4);
#pragma unroll
          for (int r = 0; r < 2; ++r) {
            acc[r][0] = bv.x; acc[r][1] = bv.y;
            acc[r][2] = bv.z; acc[r][3] = bv.w;
          }
        } else {
#pragma unroll
          for (int r = 0; r < 2; ++r)
#pragma unroll
            for (int c2 = 0; c2 < 4; ++c2) acc[r][c2] = 0.f;
        }
#pragma unroll 4
        for (int k = 0; k < D; ++k) {
          const float2 a  = *(const float2*)&aT[k][tr * 2];
          const float4 wv = f4ld(wLds + k * D + td * 4);
          const float ar[2] = {a.x, a.y};
          const float wc[4] = {wv.x, wv.y, wv.z, wv.w};
#pragma unroll
          for (int r = 0; r < 2; ++r)
#pragma unroll
            for (int c2 = 0; c2 < 4; ++c2) acc[r][c2] += ar[r] * wc[c2];
        }
        float* mp = dst + (size_t)(tr * 2) * D + td * 4;
#pragma unroll
        for (int r = 0; r < 2; ++r)
          *(float4*)(mp + (size_t)r * D) =
              make_float4(acc[r][0], acc[r][1], acc[r][2], acc[r][3]);
        __syncthreads();  // LDS reuse by next unit
      }
    }
    // pre-stage Wu chunk0 for P2 (independent of msg; hides in barrier wait)
    if (g < B) {
      const float* Wul = Wu + (size_t)l * 2 * D * D;
      float* wuC = (float*)(pool + OF_WU);
#pragma unroll
      for (int r = 0; r < 2; ++r)
        *(float4*)(wuC + (r * NTH + t) * 4) = f4ld(Wul + (r * NTH + t) * 4);
    }
    gridbar(bar + (size_t)(2 * l) * 144);

    // ===== P2 (blocks 0..63) || sw1/base precompute for l+1 (64..191) =====
    if (g < B) {
      const int b = g;
      const float* Wul = Wu + (size_t)l * 2 * D * D;
      const float* bul = bu + (size_t)l * D;
      float (*catT)[64] = (float(*)[64])pool;          // 32KB
      float* wuC = (float*)(pool + OF_WU);             // 16KB chunk

      {
        const int ii = t >> 3, q = t & 7;
        const int cI = cntL[ii], rb = rbL[ii];
        float4 a4[2];
        a4[0] = f4ld(selfmsg + ((size_t)(ii * B + b)) * D + q * 8);
        a4[1] = f4ld(selfmsg + ((size_t)(ii * B + b)) * D + q * 8 + 4);
        for (int e = 0; e < cI; ++e) {
          const float* pm = msg + ((size_t)(rb + e) * B + b) * D + q * 8;
          f4acc(a4[0], f4ld(pm));
          f4acc(a4[1], f4ld(pm + 4));
        }
        const float* ps = scur + ((size_t)(b * N + ii)) * D + q * 8;
        const float4 v0 = f4ld(ps), v1 = f4ld(ps + 4);
        const int k0 = q * 8;
        catT[k0 + 0][ii] = v0.x; catT[k0 + 1][ii] = v0.y;
        catT[k0 + 2][ii] = v0.z; catT[k0 + 3][ii] = v0.w;
        catT[k0 + 4][ii] = v1.x; catT[k0 + 5][ii] = v1.y;
        catT[k0 + 6][ii] = v1.z; catT[k0 + 7][ii] = v1.w;
        catT[D + k0 + 0][ii] = a4[0].x; catT[D + k0 + 1][ii] = a4[0].y;
        catT[D + k0 + 2][ii] = a4[0].z; catT[D + k0 + 3][ii] = a4[0].w;
        catT[D + k0 + 4][ii] = a4[1].x; catT[D + k0 + 5][ii] = a4[1].y;
        catT[D + k0 + 6][ii] = a4[1].z; catT[D + k0 + 7][ii] = a4[1].w;
      }
      __syncthreads();

      // upd GEMM, 2x4 tile: rows i = 2*tr..+2, cols d = 4*td..+4
      const int td = t & 15, tr = t >> 4;
      float acc[2][4];
      {
        const float4 bv = f4ld(bul + td * 4);
#pragma unroll
        for (int r = 0; r < 2; ++r) {
          acc[r][0] = bv.x; acc[r][1] = bv.y;
          acc[r][2] = bv.z; acc[r][3] = bv.w;
        }
      }
#pragma unroll 4
      for (int k = 0; k < 64; ++k) {
        const float2 a  = *(const float2*)&catT[k][tr * 2];
        const float4 wv = f4ld(wuC + k * D + td * 4);
        const float ar[2] = {a.x, a.y};
        const float wc[4] = {wv.x, wv.y, wv.z, wv.w};
#pragma unroll
        for (int r = 0; r < 2; ++r)
#pragma unroll
          for (int c2 = 0; c2 < 4; ++c2) acc[r][c2] += ar[r] * wc[c2];
      }
      __syncthreads();
#pragma unroll
      for (int r = 0; r < 2; ++r)
        *(float4*)(wuC + (r * NTH + t) * 4) = f4ld(Wul + 64 * D + (r * NTH + t) * 4);
      __syncthreads();
#pragma unroll 4
      for (int k = 0; k < 64; ++k) {
        const float2 a  = *(const float2*)&catT[64 + k][tr * 2];
        const float4 wv = f4ld(wuC + k * D + td * 4);
        const float ar[2] = {a.x, a.y};
        const float wc[4] = {wv.x, wv.y, wv.z, wv.w};
#pragma unroll
        for (int r = 0; r < 2; ++r)
#pragma unroll
          for (int c2 = 0; c2 < 4; ++c2) acc[r][c2] += ar[r] * wc[c2];
      }
      // residual (reads catT), then overlay sb on catT
#pragma unroll
      for (int r = 0; r < 2; ++r)
#pragma unroll
        for (int c2 = 0; c2 < 4; ++c2)
          acc[r][c2] = 0.9f * acc[r][c2] + 0.1f * catT[td * 4 + c2][tr * 2 + r];
      __syncthreads();
      float (*sb)[65] = (float(*)[65])pool;
#pragma unroll
      for (int r = 0; r < 2; ++r)
#pragma unroll
        for (int c2 = 0; c2 < 4; ++c2)
          sb[tr * 2 + r][td * 4 + c2] = acc[r][c2];
      __syncthreads();

      // sequential node scan; lane d owns column d (wave 0)
      if (t < 64) {
        const int d = t;
        uint4 w = nbr4L[0];
        int c = cntL[0];
        float dg = degL[0];
        for (int ii = 0; ii < N; ++ii) {
          uint4 wn = w; int cn = c; float dgn = dg;
          if (ii < N - 1) { wn = nbr4L[ii + 1]; cn = cntL[ii + 1]; dgn = degL[ii + 1]; }
          const unsigned wd[4] = {w.x, w.y, w.z, w.w};
          float nb = 0.0f;
#pragma unroll
          for (int q = 0; q < 8; ++q) {
            const int idx = (int)((wd[q >> 2] >> ((q & 3) * 8)) & 63u);
            const float v = sb[idx][d];
            nb += (q < c) ? v : 0.0f;
          }
          if (c > 8) {
#pragma unroll
            for (int q = 8; q < 16; ++q) {
              const int idx = (int)((wd[q >> 2] >> ((q & 3) * 8)) & 63u);
              const float v = sb[idx][d];
              nb += (q < c) ? v : 0.0f;
            }
            for (int q = 16; q < c; ++q) nb += sb[nfullL[ii * 64 + q]][d];
          }
          const float avg = nb / fmaxf(dg, 1.0f);
          const float cur = sb[ii][d];
          sb[ii][d] = (dg > 0.0f) ? (0.95f * cur + 0.05f * avg) : cur;
          w = wn; c = cn; dg = dgn;
        }
        if (LAST) {
          float gg = 0.0f;
          for (int i2 = 0; i2 < N; ++i2) gg += cwL[i2] * sb[i2][d];
          float o = bo[d];
          for (int k2 = 0; k2 < D; ++k2) o += __shfl(gg, k2, 64) * Wo[k2 * D + d];
          out[(size_t)b * D + d] = o;
        }
      }
      if (!LAST) {
        __syncthreads();
        const int ii = t >> 3, q = t & 7;
        float* ps = s + ((size_t)(b * N + ii)) * D + q * 8;
        float4 v0, v1;
        v0.x = sb[ii][q * 8 + 0]; v0.y = sb[ii][q * 8 + 1];
        v0.z = sb[ii][q * 8 + 2]; v0.w = sb[ii][q * 8 + 3];
        v1.x = sb[ii][q * 8 + 4]; v1.y = sb[ii][q * 8 + 5];
        v1.z = sb[ii][q * 8 + 6]; v1.w = sb[ii][q * 8 + 7];
        *(float4*)ps = v0;
        *(float4*)(ps + 4) = v1;
      }
    } else if (!LAST && g >= 64 && g < 64 + 128) {
      // sw1/base half-units for layer l+1: u in [0,128), i = u&63, half = u>>6
      const int u = g - 64, i = u & 63, half = u >> 6;
      const int lt = l + 1;
      float4 a0 = {0,0,0,0};
      float4 bacc = {0,0,0,0};
      const int ci = cntL[i];
      for (int c2 = 0; c2 < ci; ++c2) {
        const int j2 = nfullL[i * 64 + c2];
        const float* Wp = Wm + ((size_t)((lt * N + i) * N + j2)) * (E * D);
        f4acc(a0, f4ld(Wp + (half * NTH + t) * 4));
        if (half == 0 && t < 16) {
          const float w = ew[i * N + j2];
          const float4 w3 = f4ld(Wp + 2 * D * D + t * 4);
          const float4 bv = f4ld(bm + (((size_t)lt * N + i) * N + j2) * D + t * 4);
          bacc.x += w * w3.x + bv.x; bacc.y += w * w3.y + bv.y;
          bacc.z += w * w3.z + bv.z; bacc.w += w * w3.w + bv.w;
        }
      }
      float* dstw = sw1 + ((size_t)l * N + i) * D * D;
      *(float4*)(dstw + (half * NTH + t) * 4) = a0;
      if (half == 0 && t < 16)
        *(float4*)(baseB + ((size_t)l * N + i) * D + t * 4) = bacc;
    }
    if (l < L - 1) gridbar(bar + (size_t)(2 * l + 1) * 144);
  }
}

}  // namespace

extern "C" void kernel_launch(void* const* d_in, const int* in_sizes, int n_in,
                              void* d_out, int out_size, void* d_ws, size_t ws_size,
                              hipStream_t stream)
{
  const float* x  = (const float*)d_in[0];
  const float* ew = (const float*)d_in[1];
  const float* Wm = (const float*)d_in[2];
  const float* bm = (const float*)d_in[3];
  const float* Wu = (const float*)d_in[4];
  const float* bu = (const float*)d_in[5];
  const float* Wo = (const float*)d_in[6];
  const float* bo = (const float*)d_in[7];
  float* out = (float*)d_out;

  int L = in_sizes[2] / (N * N * E * D);  // = 3
  if (L > LMAX) L = LMAX;

  hipMemsetAsync(d_ws, 0, 4096, stream);  // zero barrier counter sets
  k_fused<<<NBLK, NTH, 0, stream>>>(x, ew, Wm, bm, Wu, bu, Wo, bo, out,
                                    (char*)d_ws, L);
}

// Round 14
// 148.799 us; speedup vs baseline: 2.7765x; 1.3571x over previous
//
#include <hip/hip_runtime.h>

namespace {

constexpr int B = 64, N = 64, D = 64, E = 2 * D + 1;  // E = 129
constexpr int NBLK = 256;   // 1 block/CU
constexpr int NTH  = 512;   // 8 waves/CU
constexpr int LMAX = 3;
constexpr size_t MAXSLOT = 1024;

__device__ __forceinline__ float4 f4ld(const float* p) { return *(const float4*)p; }
__device__ __forceinline__ void f4acc(float4& a, const float4 b) {
  a.x += b.x; a.y += b.y; a.z += b.z; a.w += b.w;
}

// Grid barrier with LEADER-ONLY release fence.
// Phase 1: all 256 blocks arrive (vmcnt drained first -> their stores are in
// their XCD's L2). Phase 2: one elected leader per XCD issues __threadfence()
// (wbl2 writes back the WHOLE XCD L2, incl. other blocks' lines), then bumps
// root2; everyone waits root2 == K (number of elected leaders). Consumers
// never re-read addresses they could hold stale (buffer rotation), so no
// consumer-side invalidate is required.
__device__ __forceinline__ void gridbar(unsigned* set, unsigned* nxcd, int lead) {
  asm volatile("s_waitcnt vmcnt(0)" ::: "memory");  // my stores are in L2
  __syncthreads();
  if (threadIdx.x == 0) {
    const int g = blockIdx.x;
    unsigned* leaf  = set + (size_t)(g & 7) * 16;   // 64B apart
    unsigned* root  = set + 8 * 16;
    unsigned* root2 = set + 9 * 16;
    __hip_atomic_fetch_add(leaf, 1u, __ATOMIC_RELAXED, __HIP_MEMORY_SCOPE_AGENT);
    if (g < 8) {
      while (__hip_atomic_load(leaf, __ATOMIC_RELAXED, __HIP_MEMORY_SCOPE_AGENT)
             < (unsigned)(NBLK / 8))
        __builtin_amdgcn_s_sleep(2);
      __hip_atomic_fetch_add(root, 1u, __ATOMIC_RELAXED, __HIP_MEMORY_SCOPE_AGENT);
    }
    while (__hip_atomic_load(root, __ATOMIC_RELAXED, __HIP_MEMORY_SCOPE_AGENT) < 8u)
      __builtin_amdgcn_s_sleep(2);
    if (lead) {
      __threadfence();  // wbl2: write back this XCD's L2 (all blocks' lines)
      __hip_atomic_fetch_add(root2, 1u, __ATOMIC_RELAXED, __HIP_MEMORY_SCOPE_AGENT);
    }
    const unsigned K =
        __hip_atomic_load(nxcd, __ATOMIC_RELAXED, __HIP_MEMORY_SCOPE_AGENT);
    while (__hip_atomic_load(root2, __ATOMIC_RELAXED, __HIP_MEMORY_SCOPE_AGENT) < K)
      __builtin_amdgcn_s_sleep(2);
  }
  __syncthreads();
}

// LDS layout (bytes). Scratch [0,48K): P1 aT(16K)+wLds(16K);
// P2 catT(32K)+wuC(16K at 32K); sb overlays catT. Tables at 48K+.
constexpr int OF_WU    = 32768;
constexpr int OF_TB    = 49152;
constexpr int OF_NBR4  = OF_TB;           // 1024
constexpr int OF_DEG   = OF_TB + 1024;
constexpr int OF_CW    = OF_TB + 1280;
constexpr int OF_CNT   = OF_TB + 1536;
constexpr int OF_RB    = OF_TB + 1792;
constexpr int OF_BTMP  = OF_TB + 2048;
constexpr int OF_NE    = OF_TB + 2304;
constexpr int OF_EI    = OF_TB + 2320;    // 2048
constexpr int OF_NFULL = OF_TB + 4368;    // 4096
constexpr int POOLSZ   = 57856;

__global__ __launch_bounds__(NTH) void k_fused(
    const float* __restrict__ x,   // [B][N][D]
    const float* __restrict__ ew,  // [N][N]
    const float* __restrict__ Wm,  // [L][N][N][E][D]
    const float* __restrict__ bm,  // [L][N][N][D]
    const float* __restrict__ Wu,  // [L][2D][D]
    const float* __restrict__ bu,  // [L][D]
    const float* __restrict__ Wo,  // [D][D]
    const float* __restrict__ bo,  // [D]
    float* __restrict__ out,       // [B][D]
    char* __restrict__ ws, int L)
{
  // barrier region (memset 4KB each launch):
  //   sets 0..4: 160 uints each (leaf 8x16, root, root2)  -> bytes [0,3200)
  //   elect[8]: byte 3328, stride 64B                     -> [3328,3840)
  //   nxcd:     byte 3840
  unsigned* bar  = (unsigned*)ws;
  unsigned* nxcd = bar + 960;
  char* p = ws + 4096;
  float* sbuf0   = (float*)p; p += (size_t)B * N * D * 4;
  float* sbuf1   = (float*)p; p += (size_t)B * N * D * 4;
  float* selfm   = (float*)p; p += (size_t)LMAX * N * B * D * 4;   // per layer
  float* msgBuf  = (float*)p; p += (size_t)LMAX * MAXSLOT * B * D * 4;  // per layer
  float* sw1     = (float*)p; p += (size_t)(LMAX - 1) * N * D * D * 4;
  float* baseB   = (float*)p;               // [LMAX-1][N][D]

  __shared__ __align__(16) char pool[POOLSZ];
  float (*aT)[64] = (float(*)[64])pool;                 // 16KB
  float* wLds  = (float*)(pool + 16384);                // 16KB
  uint4* nbr4L = (uint4*)(pool + OF_NBR4);
  float* degL  = (float*)(pool + OF_DEG);
  float* cwL   = (float*)(pool + OF_CW);
  int*   cntL  = (int*)(pool + OF_CNT);
  int*   rbL   = (int*)(pool + OF_RB);
  float* baseTmp = (float*)(pool + OF_BTMP);
  int*   neL   = (int*)(pool + OF_NE);
  unsigned short* eiL = (unsigned short*)(pool + OF_EI);
  unsigned char* nfullL = (unsigned char*)(pool + OF_NFULL);

  const int g = blockIdx.x, t = threadIdx.x;

  // ---- per-XCD leader election (mapping-independent, deadlock-safe) ----
  int lead = 0;
  if (t == 0) {
    unsigned xcd = 0;
    asm volatile("s_getreg_b32 %0, hwreg(HW_REG_XCC_ID)" : "=s"(xcd));
    unsigned* elect = bar + 832 + (size_t)(xcd & 7) * 16;
    if (__hip_atomic_fetch_add(elect, 1u, __ATOMIC_RELAXED,
                               __HIP_MEMORY_SCOPE_AGENT) == 0u) {
      lead = 1;
      __hip_atomic_fetch_add(nxcd, 1u, __ATOMIC_RELAXED,
                             __HIP_MEMORY_SCOPE_AGENT);
    }
  }

  // ---- prep: redundant per block, no cross-block deps ----
  {
    float* ewL = (float*)pool;  // overlay on aT
#pragma unroll
    for (int r = 0; r < 2; ++r)
      ((float4*)ewL)[r * NTH + t] = ((const float4*)ew)[r * NTH + t];
    __syncthreads();
    if (t < 64) {
      float rowsum = 0.f; int rc = 0;
      for (int j = 0; j < N; ++j) {
        const float v = ewL[t * N + j];
        rowsum += v; rc += (v > 0.f) ? 1 : 0;
      }
      int pre = rc;
#pragma unroll
      for (int off = 1; off < 64; off <<= 1) {
        int v = __shfl_up(pre, off, 64);
        if (t >= off) pre += v;
      }
      const int base = pre - rc;
      rbL[t] = base;
      unsigned long long lo = 0ull, hi = 0ull; int c = 0;
      for (int j = 0; j < N; ++j) {
        const float v = ewL[t * N + j];
        if (v > 0.f) {
          eiL[base + c] = (unsigned short)((t << 6) | j);
          if (c < 8)       lo |= (unsigned long long)j << (c * 8);
          else if (c < 16) hi |= (unsigned long long)j << ((c - 8) * 8);
          nfullL[t * 64 + c] = (unsigned char)j;
          ++c;
        }
      }
      uint4 w4;
      w4.x = (unsigned)lo; w4.y = (unsigned)(lo >> 32);
      w4.z = (unsigned)hi; w4.w = (unsigned)(hi >> 32);
      nbr4L[t] = w4; cntL[t] = c; degL[t] = (float)c;
      float tot = rowsum;
#pragma unroll
      for (int off = 32; off >= 1; off >>= 1) tot += __shfl_xor(tot, off, 64);
      cwL[t] = rowsum / (tot + 1e-8f);
      if (t == 63) *neL = base + rc;
    }
    __syncthreads();
  }
  const int ne = *neL;

  for (int l = 0; l < L; ++l) {
    const float* scur = (l == 0) ? x : ((l & 1) ? sbuf1 : sbuf0);
    float* sout = (l & 1) ? sbuf0 : sbuf1;   // alternate: no rewrite in launch
    float* msgl  = msgBuf + (size_t)l * MAXSLOT * B * D;
    float* selfl = selfm + (size_t)l * N * B * D;
    const bool LAST = (l == L - 1);

    // ===== P1: edge GEMMs (K=64) + self GEMMs, 512 threads/unit =====
    {
      const int U = ne + N;
      for (int u = g; u < U; u += NBLK) {
        const bool self = (u >= ne);
        int i, jj; float* dst;
        if (self) { i = u - ne; jj = i; dst = selfl + (size_t)i * B * D; }
        else {
          const int e = eiL[u]; i = e >> 6; jj = e & 63;
          dst = msgl + (size_t)u * B * D;
        }
        // stage A^T from scur[:, jj]
        {
          const int bb = t >> 3, q = t & 7;
          const float* ps = scur + ((size_t)(bb * N + jj)) * D + q * 8;
          const float4 v0 = f4ld(ps), v1 = f4ld(ps + 4);
          const int k0 = q * 8;
          aT[k0 + 0][bb] = v0.x; aT[k0 + 1][bb] = v0.y;
          aT[k0 + 2][bb] = v0.z; aT[k0 + 3][bb] = v0.w;
          aT[k0 + 4][bb] = v1.x; aT[k0 + 5][bb] = v1.y;
          aT[k0 + 6][bb] = v1.z; aT[k0 + 7][bb] = v1.w;
        }
        // stage W (16KB) + base
        if (!self) {
          const int e = eiL[u];
          const float* wsrc = Wm + ((size_t)((l * N + (e >> 6)) * N + (e & 63))) * (E * D) + D * D;
#pragma unroll
          for (int r = 0; r < 2; ++r)
            *(float4*)(wLds + (r * NTH + t) * 4) = f4ld(wsrc + (r * NTH + t) * 4);
        } else if (l > 0) {
          const float* wsrc = sw1 + ((size_t)(l - 1) * N + i) * D * D;
#pragma unroll
          for (int r = 0; r < 2; ++r)
            *(float4*)(wLds + (r * NTH + t) * 4) = f4ld(wsrc + (r * NTH + t) * 4);
          if (t < 16)
            *(float4*)(baseTmp + t * 4) = f4ld(baseB + ((size_t)(l - 1) * N + i) * D + t * 4);
        } else {
          // l==0 self: inline W1-sum over neighbors + base (read-only inputs)
          float4 a0 = {0,0,0,0}, a1 = {0,0,0,0};
          float4 bacc = {0,0,0,0};
          const int ci = cntL[i];
          for (int c2 = 0; c2 < ci; ++c2) {
            const int j2 = nfullL[i * 64 + c2];
            const float* Wp = Wm + ((size_t)(i * N + j2)) * (E * D);
            f4acc(a0, f4ld(Wp + (0 * NTH + t) * 4));
            f4acc(a1, f4ld(Wp + (1 * NTH + t) * 4));
            if (t < 16) {
              const float w = ew[i * N + j2];
              const float4 w3 = f4ld(Wp + 2 * D * D + t * 4);
              const float4 bv = f4ld(bm + ((size_t)(i * N + j2)) * D + t * 4);
              bacc.x += w * w3.x + bv.x; bacc.y += w * w3.y + bv.y;
              bacc.z += w * w3.z + bv.z; bacc.w += w * w3.w + bv.w;
            }
          }
          *(float4*)(wLds + (0 * NTH + t) * 4) = a0;
          *(float4*)(wLds + (1 * NTH + t) * 4) = a1;
          if (t < 16) *(float4*)(baseTmp + t * 4) = bacc;
        }
        __syncthreads();

        // 2x4 register tile: rows b = 2*tr..+2, cols d = 4*td..+4
        const int td = t & 15, tr = t >> 4;
        float acc[2][4];
        if (self) {
          const float4 bv = f4ld(baseTmp + td * 4);
#pragma unroll
          for (int r = 0; r < 2; ++r) {
            acc[r][0] = bv.x; acc[r][1] = bv.y;
            acc[r][2] = bv.z; acc[r][3] = bv.w;
          }
        } else {
#pragma unroll
          for (int r = 0; r < 2; ++r)
#pragma unroll
            for (int c2 = 0; c2 < 4; ++c2) acc[r][c2] = 0.f;
        }
#pragma unroll 4
        for (int k = 0; k < D; ++k) {
          const float2 a  = *(const float2*)&aT[k][tr * 2];
          const float4 wv = f4ld(wLds + k * D + td * 4);
          const float ar[2] = {a.x, a.y};
          const float wc[4] = {wv.x, wv.y, wv.z, wv.w};
#pragma unroll
          for (int r = 0; r < 2; ++r)
#pragma unroll
            for (int c2 = 0; c2 < 4; ++c2) acc[r][c2] += ar[r] * wc[c2];
        }
        float* mp = dst + (size_t)(tr * 2) * D + td * 4;
#pragma unroll
        for (int r = 0; r < 2; ++r)
          *(float4*)(mp + (size_t)r * D) =
              make_float4(acc[r][0], acc[r][1], acc[r][2], acc[r][3]);
        __syncthreads();  // LDS reuse by next unit
      }
    }
    // pre-stage Wu chunk0 for P2 (read-only; hides in barrier wait)
    if (g < B) {
      const float* Wul = Wu + (size_t)l * 2 * D * D;
      float* wuC = (float*)(pool + OF_WU);
#pragma unroll
      for (int r = 0; r < 2; ++r)
        *(float4*)(wuC + (r * NTH + t) * 4) = f4ld(Wul + (r * NTH + t) * 4);
    }
    gridbar(bar + (size_t)(2 * l) * 160, nxcd, lead);

    // ===== P2 (blocks 0..63) || sw1/base precompute for l+1 (64..191) =====
    if (g < B) {
      const int b = g;
      const float* Wul = Wu + (size_t)l * 2 * D * D;
      const float* bul = bu + (size_t)l * D;
      float (*catT)[64] = (float(*)[64])pool;          // 32KB
      float* wuC = (float*)(pool + OF_WU);             // 16KB chunk

      {
        const int ii = t >> 3, q = t & 7;
        const int cI = cntL[ii], rb = rbL[ii];
        float4 a4[2];
        a4[0] = f4ld(selfl + ((size_t)(ii * B + b)) * D + q * 8);
        a4[1] = f4ld(selfl + ((size_t)(ii * B + b)) * D + q * 8 + 4);
        for (int e = 0; e < cI; ++e) {
          const float* pm = msgl + ((size_t)(rb + e) * B + b) * D + q * 8;
          f4acc(a4[0], f4ld(pm));
          f4acc(a4[1], f4ld(pm + 4));
        }
        const float* ps = scur + ((size_t)(b * N + ii)) * D + q * 8;
        const float4 v0 = f4ld(ps), v1 = f4ld(ps + 4);
        const int k0 = q * 8;
        catT[k0 + 0][ii] = v0.x; catT[k0 + 1][ii] = v0.y;
        catT[k0 + 2][ii] = v0.z; catT[k0 + 3][ii] = v0.w;
        catT[k0 + 4][ii] = v1.x; catT[k0 + 5][ii] = v1.y;
        catT[k0 + 6][ii] = v1.z; catT[k0 + 7][ii] = v1.w;
        catT[D + k0 + 0][ii] = a4[0].x; catT[D + k0 + 1][ii] = a4[0].y;
        catT[D + k0 + 2][ii] = a4[0].z; catT[D + k0 + 3][ii] = a4[0].w;
        catT[D + k0 + 4][ii] = a4[1].x; catT[D + k0 + 5][ii] = a4[1].y;
        catT[D + k0 + 6][ii] = a4[1].z; catT[D + k0 + 7][ii] = a4[1].w;
      }
      __syncthreads();

      // upd GEMM, 2x4 tile: rows i = 2*tr..+2, cols d = 4*td..+4
      const int td = t & 15, tr = t >> 4;
      float acc[2][4];
      {
        const float4 bv = f4ld(bul + td * 4);
#pragma unroll
        for (int r = 0; r < 2; ++r) {
          acc[r][0] = bv.x; acc[r][1] = bv.y;
          acc[r][2] = bv.z; acc[r][3] = bv.w;
        }
      }
#pragma unroll 4
      for (int k = 0; k < 64; ++k) {
        const float2 a  = *(const float2*)&catT[k][tr * 2];
        const float4 wv = f4ld(wuC + k * D + td * 4);
        const float ar[2] = {a.x, a.y};
        const float wc[4] = {wv.x, wv.y, wv.z, wv.w};
#pragma unroll
        for (int r = 0; r < 2; ++r)
#pragma unroll
          for (int c2 = 0; c2 < 4; ++c2) acc[r][c2] += ar[r] * wc[c2];
      }
      __syncthreads();
#pragma unroll
      for (int r = 0; r < 2; ++r)
        *(float4*)(wuC + (r * NTH + t) * 4) = f4ld(Wul + 64 * D + (r * NTH + t) * 4);
      __syncthreads();
#pragma unroll 4
      for (int k = 0; k < 64; ++k) {
        const float2 a  = *(const float2*)&catT[64 + k][tr * 2];
        const float4 wv = f4ld(wuC + k * D + td * 4);
        const float ar[2] = {a.x, a.y};
        const float wc[4] = {wv.x, wv.y, wv.z, wv.w};
#pragma unroll
        for (int r = 0; r < 2; ++r)
#pragma unroll
          for (int c2 = 0; c2 < 4; ++c2) acc[r][c2] += ar[r] * wc[c2];
      }
      // residual (reads catT), then overlay sb on catT
#pragma unroll
      for (int r = 0; r < 2; ++r)
#pragma unroll
        for (int c2 = 0; c2 < 4; ++c2)
          acc[r][c2] = 0.9f * acc[r][c2] + 0.1f * catT[td * 4 + c2][tr * 2 + r];
      __syncthreads();
      float (*sb)[65] = (float(*)[65])pool;
#pragma unroll
      for (int r = 0; r < 2; ++r)
#pragma unroll
        for (int c2 = 0; c2 < 4; ++c2)
          sb[tr * 2 + r][td * 4 + c2] = acc[r][c2];
      __syncthreads();

      // sequential node scan; lane d owns column d (wave 0)
      if (t < 64) {
        const int d = t;
        uint4 w = nbr4L[0];
        int c = cntL[0];
        float dg = degL[0];
        for (int ii = 0; ii < N; ++ii) {
          uint4 wn = w; int cn = c; float dgn = dg;
          if (ii < N - 1) { wn = nbr4L[ii + 1]; cn = cntL[ii + 1]; dgn = degL[ii + 1]; }
          const unsigned wd[4] = {w.x, w.y, w.z, w.w};
          float nb = 0.0f;
#pragma unroll
          for (int q = 0; q < 8; ++q) {
            const int idx = (int)((wd[q >> 2] >> ((q & 3) * 8)) & 63u);
            const float v = sb[idx][d];
            nb += (q < c) ? v : 0.0f;
          }
          if (c > 8) {
#pragma unroll
            for (int q = 8; q < 16; ++q) {
              const int idx = (int)((wd[q >> 2] >> ((q & 3) * 8)) & 63u);
              const float v = sb[idx][d];
              nb += (q < c) ? v : 0.0f;
            }
            for (int q = 16; q < c; ++q) nb += sb[nfullL[ii * 64 + q]][d];
          }
          const float avg = nb / fmaxf(dg, 1.0f);
          const float cur = sb[ii][d];
          sb[ii][d] = (dg > 0.0f) ? (0.95f * cur + 0.05f * avg) : cur;
          w = wn; c = cn; dg = dgn;
        }
        if (LAST) {
          float gg = 0.0f;
          for (int i2 = 0; i2 < N; ++i2) gg += cwL[i2] * sb[i2][d];
          float o = bo[d];
          for (int k2 = 0; k2 < D; ++k2) o += __shfl(gg, k2, 64) * Wo[k2 * D + d];
          out[(size_t)b * D + d] = o;
        }
      }
      if (!LAST) {
        __syncthreads();
        const int ii = t >> 3, q = t & 7;
        float* ps = sout + ((size_t)(b * N + ii)) * D + q * 8;
        float4 v0, v1;
        v0.x = sb[ii][q * 8 + 0]; v0.y = sb[ii][q * 8 + 1];
        v0.z = sb[ii][q * 8 + 2]; v0.w = sb[ii][q * 8 + 3];
        v1.x = sb[ii][q * 8 + 4]; v1.y = sb[ii][q * 8 + 5];
        v1.z = sb[ii][q * 8 + 6]; v1.w = sb[ii][q * 8 + 7];
        *(float4*)ps = v0;
        *(float4*)(ps + 4) = v1;
      }
    } else if (!LAST && g >= 64 && g < 64 + 128) {
      // sw1/base half-units for layer l+1: u in [0,128), i = u&63, half = u>>6
      const int u = g - 64, i = u & 63, half = u >> 6;
      const int lt = l + 1;
      float4 a0 = {0,0,0,0};
      float4 bacc = {0,0,0,0};
      const int ci = cntL[i];
      for (int c2 = 0; c2 < ci; ++c2) {
        const int j2 = nfullL[i * 64 + c2];
        const float* Wp = Wm + ((size_t)((lt * N + i) * N + j2)) * (E * D);
        f4acc(a0, f4ld(Wp + (half * NTH + t) * 4));
        if (half == 0 && t < 16) {
          const float w = ew[i * N + j2];
          const float4 w3 = f4ld(Wp + 2 * D * D + t * 4);
          const float4 bv = f4ld(bm + (((size_t)lt * N + i) * N + j2) * D + t * 4);
          bacc.x += w * w3.x + bv.x; bacc.y += w * w3.y + bv.y;
          bacc.z += w * w3.z + bv.z; bacc.w += w * w3.w + bv.w;
        }
      }
      float* dstw = sw1 + ((size_t)l * N + i) * D * D;
      *(float4*)(dstw + (half * NTH + t) * 4) = a0;
      if (half == 0 && t < 16)
        *(float4*)(baseB + ((size_t)l * N + i) * D + t * 4) = bacc;
    }
    if (l < L - 1) gridbar(bar + (size_t)(2 * l + 1) * 160, nxcd, lead);
  }
}

}  // namespace

extern "C" void kernel_launch(void* const* d_in, const int* in_sizes, int n_in,
                              void* d_out, int out_size, void* d_ws, size_t ws_size,
                              hipStream_t stream)
{
  const float* x  = (const float*)d_in[0];
  const float* ew = (const float*)d_in[1];
  const float* Wm = (const float*)d_in[2];
  const float* bm = (const float*)d_in[3];
  const float* Wu = (const float*)d_in[4];
  const float* bu = (const float*)d_in[5];
  const float* Wo = (const float*)d_in[6];
  const float* bo = (const float*)d_in[7];
  float* out = (float*)d_out;

  int L = in_sizes[2] / (N * N * E * D);  // = 3
  if (L > LMAX) L = LMAX;

  hipMemsetAsync(d_ws, 0, 4096, stream);  // zero barrier/election counters
  k_fused<<<NBLK, NTH, 0, stream>>>(x, ew, Wm, bm, Wu, bu, Wo, bo, out,
                                    (char*)d_ws, L);
}